// Round 10
// baseline (541.157 us; speedup 1.0000x reference)
//
#include <hip/hip_runtime.h>
#include <cstdint>
#include <cstddef>

typedef __bf16 bf16x8 __attribute__((ext_vector_type(8)));
typedef float f32x4 __attribute__((ext_vector_type(4)));
typedef unsigned short u16x8 __attribute__((ext_vector_type(8)));
typedef unsigned short u16x4 __attribute__((ext_vector_type(4)));
typedef unsigned int u32x2 __attribute__((ext_vector_type(2)));

#define VT_LD 56   // padded j-stride of V^T rows
#define BSTRIDE 52 // bias/mask row stride (elements)
#define BSZ 2548   // 49*52 per head / per window
#define PLD 72     // P LDS row stride (shorts): 144B -> 2-way banks (free)

__device__ __forceinline__ unsigned short f2bf(float f) {
  unsigned int u = __builtin_bit_cast(unsigned int, f);
  u += 0x7FFFu + ((u >> 16) & 1u);   // RNE
  return (unsigned short)(u >> 16);
}
__device__ __forceinline__ float bf2f(unsigned short h) {
  unsigned int u = (unsigned int)h << 16;
  return __builtin_bit_cast(float, u);
}

__device__ __forceinline__ void gload_lds16(const void* g, void* l) {
  __builtin_amdgcn_global_load_lds((const __attribute__((address_space(1))) void*)g,
                                   (__attribute__((address_space(3))) void*)l, 16, 0, 0);
}

// ---------------- kernel 0: generic fp32 -> bf16 (vec8, grid-stride) ----------------
__global__ void conv_f2b_k(const float* __restrict__ src, unsigned short* __restrict__ dst, long n8) {
  long i = (long)blockIdx.x * blockDim.x + threadIdx.x;
  long stride = (long)gridDim.x * blockDim.x;
  for (; i < n8; i += stride) {
    float4 a = *(const float4*)(src + i * 8);
    float4 b = *(const float4*)(src + i * 8 + 4);
    u16x8 p;
    p[0]=f2bf(a.x); p[1]=f2bf(a.y); p[2]=f2bf(a.z); p[3]=f2bf(a.w);
    p[4]=f2bf(b.x); p[5]=f2bf(b.y); p[6]=f2bf(b.z); p[7]=f2bf(b.w);
    *(u16x8*)(dst + i * 8) = p;
  }
}

// ---------------- kernel 0b: bias table bf16 [16][49][52] (pad cols 49..51 = 0) ----------------
__global__ void build_bias_k(const float* __restrict__ rpb, unsigned short* __restrict__ biasT) {
  int idx = blockIdx.x * 256 + threadIdx.x;
  if (idx >= 16 * BSZ) return;
  int h = idx / BSZ;
  int rem = idx - h * BSZ;
  int i = rem / BSTRIDE, j = rem - (rem / BSTRIDE) * BSTRIDE;
  unsigned short v = 0;
  if (j < 49) {
    int r1 = i / 7, c1 = i - r1 * 7;
    int r2 = j / 7, c2 = j - r2 * 7;
    int ri = (r1 - r2 + 6) * 13 + (c1 - c2 + 6);
    v = f2bf(rpb[ri * 16 + h]);
  }
  biasT[idx] = v;
}

// ---------------- kernel 0c: padded fp32 mask [64][49][52] (16B-aligned rows) ----------------
__global__ void build_maskp_k(const float* __restrict__ mask, float* __restrict__ maskp) {
  int idx = blockIdx.x * 256 + threadIdx.x;   // grid exact: 64*2548 = 637*256
  int w = idx / BSZ;
  int rem = idx - w * BSZ;
  int i = rem / BSTRIDE, j = rem - (rem / BSTRIDE) * BSTRIDE;
  maskp[idx] = (j < 49) ? mask[w * 2401 + i * 49 + j] : 0.0f;
}

// Common staging/frag-read setup for the 128x128 BK=32 2-phase K-loop.
#define GEMM_SETUP(N0)                                                         \
  int t = threadIdx.x;                                                         \
  int lane = t & 63, wv = t >> 6;                                              \
  int g = lane >> 4, q = lane & 15;                                            \
  int wrow = wv >> 1, wcol = wv & 1;                                           \
  f32x4 acc[4][4] = {};                                                        \
  int schunk = (t & 3) ^ ((t >> 3) & 3);                                       \
  const unsigned short* ag0 = xb + (m0 + (t >> 2)) * 512 + schunk * 8;         \
  const unsigned short* ag1 = ag0 + 64 * 512;                                  \
  const unsigned short* bg0 = wb + (size_t)((N0) + (t >> 2)) * 512 + schunk * 8; \
  const unsigned short* bg1 = bg0 + 64 * 512;                                  \
  unsigned short* alA  = Ab + wv * 512;                                        \
  unsigned short* alA2 = Ab + 2048 + wv * 512;                                 \
  unsigned short* blB  = Bb + wv * 512;                                        \
  unsigned short* blB2 = Bb + 2048 + wv * 512;                                 \
  int roff = (8 * g) ^ (((q >> 1) & 3) << 3);                                  \
  const unsigned short* arb = Ab + (wrow * 64 + q) * 32 + roff;                \
  const unsigned short* brb = Bb + (wcol * 64 + q) * 32 + roff;

#define STAGE(KT, BOFF) do {                    \
    int kof = (KT) * 32;                        \
    gload_lds16(ag0 + kof, alA  + (BOFF));      \
    gload_lds16(ag1 + kof, alA2 + (BOFF));      \
    gload_lds16(bg0 + kof, blB  + (BOFF));      \
    gload_lds16(bg1 + kof, blB2 + (BOFF));      \
  } while (0)

// SWAPPED=0: acc[i2][j2] r -> m=wrow*64+i2*16+4g+r, n=wcol*64+j2*16+q  (V kernel)
// SWAPPED=1: acc[i2][j2] r -> n=wcol*64+j2*16+4g+r, m=wrow*64+i2*16+q  (Q/K kernel)
#define COMPUTE(BOFF, SWAPPED) do {                                            \
    bf16x8 af[4], bfr[4];                                                      \
    _Pragma("unroll")                                                          \
    for (int i2 = 0; i2 < 4; ++i2) af[i2]  = *(const bf16x8*)(arb + (BOFF) + i2 * 512); \
    _Pragma("unroll")                                                          \
    for (int j2 = 0; j2 < 4; ++j2) bfr[j2] = *(const bf16x8*)(brb + (BOFF) + j2 * 512); \
    _Pragma("unroll")                                                          \
    for (int i2 = 0; i2 < 4; ++i2)                                             \
      _Pragma("unroll")                                                        \
      for (int j2 = 0; j2 < 4; ++j2)                                           \
        acc[i2][j2] = (SWAPPED)                                                \
          ? __builtin_amdgcn_mfma_f32_16x16x32_bf16(bfr[j2], af[i2], acc[i2][j2], 0, 0, 0) \
          : __builtin_amdgcn_mfma_f32_16x16x32_bf16(af[i2], bfr[j2], acc[i2][j2], 0, 0, 0); \
  } while (0)

#define KLOOP(SWAPPED)                          \
  STAGE(0, 0);                                  \
  __syncthreads();                              \
  for (int kt = 0; kt < 16; kt += 2) {          \
    STAGE(kt + 1, 4096);                        \
    COMPUTE(0, SWAPPED);                        \
    __syncthreads();                            \
    if (kt + 2 < 16) STAGE(kt + 2, 0);          \
    COMPUTE(4096, SWAPPED);                     \
    __syncthreads();                            \
  }

// ---------------- kernel 1a: Q/K GEMM (swapped operands, direct packed stores) ----------------
__global__ __launch_bounds__(256, 4) void qkv_gemm_qk_k(
    const unsigned short* __restrict__ xb, const float* __restrict__ qkv_b,
    const unsigned short* __restrict__ wb,
    unsigned short* __restrict__ qs, unsigned short* __restrict__ kk)
{
  __shared__ __align__(16) unsigned short smem[16384];
  unsigned short* Ab = smem;
  unsigned short* Bb = smem + 8192;

  int bid = blockIdx.x;
  int sw = (bid & 7) * 784 + (bid >> 3);   // 6272 % 8 == 0 -> bijective
  int mt = sw >> 3, ntl = sw & 7;
  long m0 = (long)mt * 128;
  int  n0 = ntl * 128;
  int  s  = n0 >> 9;

  GEMM_SETUP(n0)
  KLOOP(1)

  unsigned short* dst = (s == 0) ? qs : kk;
  float sc = (s == 0) ? 0.17677669529663687f : 1.0f;
  float4 bi[4];
  int hj[4], dj[4];
  #pragma unroll
  for (int j2 = 0; j2 < 4; ++j2) {
    int n = n0 + wcol * 64 + j2 * 16 + 4 * g;
    bi[j2] = *(const float4*)(qkv_b + n);
    hj[j2] = (n >> 5) & 15;
    dj[j2] = n & 31;
  }
  #pragma unroll
  for (int i2 = 0; i2 < 4; ++i2) {
    unsigned int m = (unsigned int)m0 + wrow * 64 + i2 * 16 + q;
    unsigned int b = m / 49;
    unsigned int i = m - b * 49;
    size_t base = ((size_t)(b * 16) * 49 + i) * 32;
    #pragma unroll
    for (int j2 = 0; j2 < 4; ++j2) {
      f32x4 a = acc[i2][j2];
      unsigned int lo = (unsigned int)f2bf((a[0] + bi[j2].x) * sc) | ((unsigned int)f2bf((a[1] + bi[j2].y) * sc) << 16);
      unsigned int hi = (unsigned int)f2bf((a[2] + bi[j2].z) * sc) | ((unsigned int)f2bf((a[3] + bi[j2].w) * sc) << 16);
      u32x2 wv2 = {lo, hi};
      *(u32x2*)(dst + base + (size_t)hj[j2] * (49 * 32) + dj[j2]) = wv2;
    }
  }
}

// ---------------- kernel 1b: V GEMM (normal orientation, VT packed stores) ----------------
__global__ __launch_bounds__(256, 4) void qkv_gemm_v_k(
    const unsigned short* __restrict__ xb, const float* __restrict__ qkv_b,
    const unsigned short* __restrict__ wb,
    unsigned short* __restrict__ vt)
{
  __shared__ __align__(16) unsigned short smem[16384];
  unsigned short* Ab = smem;
  unsigned short* Bb = smem + 8192;

  int bid = blockIdx.x;
  int sw = (bid & 7) * 392 + (bid >> 3);   // 3136 % 8 == 0 -> bijective
  int mt = sw >> 2, ntv = sw & 3;
  long m0 = (long)mt * 128;
  int  n0 = 1024 + ntv * 128;

  GEMM_SETUP(n0)
  KLOOP(0)

  #pragma unroll
  for (int j2 = 0; j2 < 4; ++j2) {
    int n  = n0 + wcol * 64 + j2 * 16 + q;
    float bias = qkv_b[n];
    int d = n & 31;
    int h = (n >> 5) & 15;
    #pragma unroll
    for (int i2 = 0; i2 < 4; ++i2) {
      unsigned int gm0 = (unsigned int)m0 + wrow * 64 + i2 * 16 + 4 * g;
      unsigned int b0 = gm0 / 49;
      unsigned int i0 = gm0 - b0 * 49;
      unsigned short hv[4];
      #pragma unroll
      for (int r = 0; r < 4; ++r) hv[r] = f2bf(acc[i2][j2][r] + bias);
      if (i0 <= 45) {
        unsigned short* base = vt + ((size_t)(b0 * 16 + h) * 32 + d) * VT_LD;
        if ((i0 & 1) == 0) {
          *(unsigned int*)(base + i0)     = (unsigned int)hv[0] | ((unsigned int)hv[1] << 16);
          *(unsigned int*)(base + i0 + 2) = (unsigned int)hv[2] | ((unsigned int)hv[3] << 16);
        } else {
          base[i0] = hv[0];
          *(unsigned int*)(base + i0 + 1) = (unsigned int)hv[1] | ((unsigned int)hv[2] << 16);
          base[i0 + 3] = hv[3];
        }
      } else {
        #pragma unroll
        for (int r = 0; r < 4; ++r) {
          unsigned int gm = gm0 + r;
          unsigned int b = gm / 49;
          unsigned int i = gm - b * 49;
          vt[((size_t)(b * 16 + h) * 32 + d) * VT_LD + i] = hv[r];
        }
      }
    }
  }
}

// ---------------- kernel 2: fused window attention ----------------
// swapped QK^T (rows lane-local) AND swapped PV (output d lane-local -> float4 stores)
__global__ __launch_bounds__(256, 4) void win_attn_k(
    const unsigned short* __restrict__ qs, const unsigned short* __restrict__ kk,
    const unsigned short* __restrict__ vt, const unsigned short* __restrict__ biasT,
    const float* __restrict__ maskp, float* __restrict__ out)
{
  __shared__ unsigned short plds[4][64 * PLD];   // per-wave P (no other LDS, no barriers)

  int b = blockIdx.x;
  int t = threadIdx.x;
  int lane = t & 63, wv = t >> 6;
  int g = lane >> 4, q = lane & 15;

  const float* wm = maskp + (size_t)(b & 63) * BSZ;
  unsigned short* pl = plds[wv];
  const float NINF = -__builtin_inff();

  int rc[4];
  rc[0] = q; rc[1] = 16 + q; rc[2] = 32 + q; rc[3] = 48;

  int h0 = wv * 4;
  const unsigned short* qh = qs + (size_t)(b * 16 + h0) * (49 * 32);
  const unsigned short* kh = kk + (size_t)(b * 16 + h0) * (49 * 32);
  bf16x8 ak[4], bq[4];
  #pragma unroll
  for (int jt = 0; jt < 4; ++jt) ak[jt] = *(const bf16x8*)(kh + rc[jt] * 32 + 8 * g);
  #pragma unroll
  for (int it = 0; it < 4; ++it) bq[it] = *(const bf16x8*)(qh + rc[it] * 32 + 8 * g);

  #pragma unroll
  for (int hh = 0; hh < 4; ++hh) {
    int h = wv * 4 + hh;
    const unsigned short* vh  = vt + (size_t)(b * 16 + h) * (32 * VT_LD);
    const unsigned short* bh2 = biasT + h * BSZ;

    f32x4 zero = {0.f, 0.f, 0.f, 0.f};
    f32x4 st[4][4];
    __builtin_amdgcn_s_setprio(1);
    #pragma unroll
    for (int it = 0; it < 4; ++it)
      #pragma unroll
      for (int jt = 0; jt < 4; ++jt)
        st[it][jt] = __builtin_amdgcn_mfma_f32_16x16x32_bf16(ak[jt], bq[it], zero, 0, 0, 0);
    __builtin_amdgcn_s_setprio(0);

    bf16x8 akn[4], bqn[4];
    if (hh < 3) {
      const unsigned short* qh2 = qh + 49 * 32;
      const unsigned short* kh2 = kh + 49 * 32;
      #pragma unroll
      for (int jt = 0; jt < 4; ++jt) akn[jt] = *(const bf16x8*)(kh2 + rc[jt] * 32 + 8 * g);
      #pragma unroll
      for (int it = 0; it < 4; ++it) bqn[it] = *(const bf16x8*)(qh2 + rc[it] * 32 + 8 * g);
      qh = qh2; kh = kh2;
    }
    bf16x8 bv[2][2];
    #pragma unroll
    for (int ktt = 0; ktt < 2; ++ktt)
      #pragma unroll
      for (int dt = 0; dt < 2; ++dt)
        bv[ktt][dt] = *(const bf16x8*)(vh + (dt * 16 + q) * VT_LD + ktt * 32 + 8 * g);

    // softmax: rows lane-local (i = it*16+q), j = jt*16+4g+r
    #pragma unroll
    for (int it = 0; it < 4; ++it) {
      int i = it * 16 + q;
      int ic = i > 48 ? 48 : i;
      f32x4 pv4[4];
      f32x4 vm = {NINF, NINF, NINF, NINF};
      #pragma unroll
      for (int jt = 0; jt < 4; ++jt) {
        if (jt == 3 && g > 0) {
          pv4[3] = (f32x4){NINF, NINF, NINF, NINF};
        } else {
          u16x4 bu = *(const u16x4*)(bh2 + ic * BSTRIDE + jt * 16 + 4 * g);
          f32x4 m4 = *(const f32x4*)(wm + ic * BSTRIDE + jt * 16 + 4 * g);
          f32x4 sv = st[it][jt];
          #pragma unroll
          for (int r = 0; r < 4; ++r) sv[r] += bf2f(bu[r]) + m4[r];
          if (jt == 3) {            // g==0 here: j = 48+r, valid only r==0
            sv[1] = NINF; sv[2] = NINF; sv[3] = NINF;
          }
          pv4[jt] = sv;
          #pragma unroll
          for (int r = 0; r < 4; ++r) vm[r] = fmaxf(vm[r], sv[r]);
        }
      }
      float mx = fmaxf(fmaxf(vm[0], vm[1]), fmaxf(vm[2], vm[3]));
      mx = fmaxf(mx, __shfl_xor(mx, 16));
      mx = fmaxf(mx, __shfl_xor(mx, 32));
      f32x4 vs = zero;
      #pragma unroll
      for (int jt = 0; jt < 4; ++jt) {
        #pragma unroll
        for (int r = 0; r < 4; ++r) {
          float p = __expf(pv4[jt][r] - mx);
          pv4[jt][r] = p;
          vs[r] += p;
        }
      }
      float sm = (vs[0] + vs[1]) + (vs[2] + vs[3]);
      sm += __shfl_xor(sm, 16);
      sm += __shfl_xor(sm, 32);
      float rv = 1.0f / sm;
      #pragma unroll
      for (int jt = 0; jt < 4; ++jt) {
        unsigned int lo = (unsigned int)f2bf(pv4[jt][0] * rv) | ((unsigned int)f2bf(pv4[jt][1] * rv) << 16);
        unsigned int hi = (unsigned int)f2bf(pv4[jt][2] * rv) | ((unsigned int)f2bf(pv4[jt][3] * rv) << 16);
        u32x2 w = {lo, hi};
        *(u32x2*)(pl + i * PLD + jt * 16 + 4 * g) = w;
      }
    }

    // O = P @ V, SWAPPED: oacc[it][dt] r -> d = dt*16+4g+r, i = it*16+q (lane-local)
    f32x4 oacc[4][2] = {};
    #pragma unroll
    for (int ktt = 0; ktt < 2; ++ktt) {
      bf16x8 pa[4];
      #pragma unroll
      for (int it = 0; it < 4; ++it)
        pa[it] = *(const bf16x8*)(pl + (it * 16 + q) * PLD + ktt * 32 + 8 * g);
      __builtin_amdgcn_s_setprio(1);
      #pragma unroll
      for (int it = 0; it < 4; ++it)
        #pragma unroll
        for (int dt = 0; dt < 2; ++dt)
          oacc[it][dt] = __builtin_amdgcn_mfma_f32_16x16x32_bf16(bv[ktt][dt], pa[it], oacc[it][dt], 0, 0, 0);
      __builtin_amdgcn_s_setprio(0);
    }

    // store fp32 output: per lane float4 at [b*49+i][h*32 + dt*16 + 4g]
    #pragma unroll
    for (int it = 0; it < 4; ++it) {
      int i = it * 16 + q;
      if (i < 49) {
        float* orow = out + (size_t)(b * 49 + i) * 512 + h * 32 + 4 * g;
        #pragma unroll
        for (int dt = 0; dt < 2; ++dt)
          *(f32x4*)(orow + dt * 16) = oacc[it][dt];
      }
    }

    if (hh < 3) {
      #pragma unroll
      for (int jt = 0; jt < 4; ++jt) ak[jt] = akn[jt];
      #pragma unroll
      for (int it = 0; it < 4; ++it) bq[it] = bqn[it];
    }
  }
}

// ---------------- launcher ----------------
extern "C" void kernel_launch(void* const* d_in, const int* in_sizes, int n_in,
                              void* d_out, int out_size, void* d_ws, size_t ws_size,
                              hipStream_t stream) {
  const float* x     = (const float*)d_in[0];
  const float* mask  = (const float*)d_in[1];
  const float* qkv_w = (const float*)d_in[2];
  const float* qkv_b = (const float*)d_in[3];
  const float* rpb   = (const float*)d_in[4];
  float* out = (float*)d_out;

  // workspace layout (bytes)
  const size_t QS_OFF   = 0;                         // 2048*16*49*32*2 = 102,760,448
  const size_t KK_OFF   = 102760448;
  const size_t VT_OFF   = 205520896;                 // 2048*16*32*56*2 = 117,440,512
  const size_t BIAS_OFF = 322961408;                 // 16*2548*2      = 81,536
  const size_t WB_OFF   = 323042944;                 // 1536*512*2     = 1,572,864
  const size_t NEED     = 324615808;
  if (ws_size < NEED) return;

  char* ws = (char*)d_ws;
  unsigned short* qsb   = (unsigned short*)(ws + QS_OFF);
  unsigned short* kkb   = (unsigned short*)(ws + KK_OFF);
  unsigned short* vtb   = (unsigned short*)(ws + VT_OFF);
  unsigned short* biasT = (unsigned short*)(ws + BIAS_OFF);
  unsigned short* wb    = (unsigned short*)(ws + WB_OFF);
  // maskp (64*2548*4 = 652,288 B) OVERLAYS the wb region (1,572,864 B):
  // wb is dead after the GEMMs; maskp is built after them, read only by attn.
  float*          maskp = (float*)(ws + WB_OFF);

  // xb (bf16 x, 103 MB) lives in d_out (205 MB fp32) — dead until win_attn
  // fully overwrites it.
  unsigned short* xb = (unsigned short*)d_out;

  conv_f2b_k<<<2048, 256, 0, stream>>>(x, xb, 6422528);        // 100352*512/8
  conv_f2b_k<<<512, 256, 0, stream>>>(qkv_w, wb, 98304);       // 1536*512/8
  build_bias_k<<<160, 256, 0, stream>>>(rpb, biasT);           // 16*2548
  qkv_gemm_v_k<<<3136, 256, 0, stream>>>(xb, qkv_b, wb, vtb);
  qkv_gemm_qk_k<<<6272, 256, 0, stream>>>(xb, qkv_b, wb, qsb, kkb);
  build_maskp_k<<<637, 256, 0, stream>>>(mask, maskp);         // after GEMMs (wb overlay)
  win_attn_k<<<2048, 256, 0, stream>>>(qsb, kkb, vtb, biasT, maskp, out);
}

// Round 11
// 458.169 us; speedup vs baseline: 1.1811x; 1.1811x over previous
//
#include <hip/hip_runtime.h>
#include <cstdint>
#include <cstddef>

typedef __bf16 bf16x8 __attribute__((ext_vector_type(8)));
typedef float f32x4 __attribute__((ext_vector_type(4)));
typedef unsigned short u16x8 __attribute__((ext_vector_type(8)));
typedef unsigned short u16x4 __attribute__((ext_vector_type(4)));
typedef unsigned int u32x2 __attribute__((ext_vector_type(2)));

#define VT_LD 56   // padded j-stride of V^T rows
#define BSTRIDE 52 // bias/mask row stride (elements)
#define BSZ 2548   // 49*52 per head
#define PLD 80     // P LDS row stride (shorts) — R6-proven config

__device__ __forceinline__ unsigned short f2bf(float f) {
  unsigned int u = __builtin_bit_cast(unsigned int, f);
  u += 0x7FFFu + ((u >> 16) & 1u);   // RNE
  return (unsigned short)(u >> 16);
}
__device__ __forceinline__ float bf2f(unsigned short h) {
  unsigned int u = (unsigned int)h << 16;
  return __builtin_bit_cast(float, u);
}

__device__ __forceinline__ void gload_lds16(const void* g, void* l) {
  __builtin_amdgcn_global_load_lds((const __attribute__((address_space(1))) void*)g,
                                   (__attribute__((address_space(3))) void*)l, 16, 0, 0);
}

// ---------------- kernel 0: generic fp32 -> bf16 (vec8, grid-stride) ----------------
__global__ void conv_f2b_k(const float* __restrict__ src, unsigned short* __restrict__ dst, long n8) {
  long i = (long)blockIdx.x * blockDim.x + threadIdx.x;
  long stride = (long)gridDim.x * blockDim.x;
  for (; i < n8; i += stride) {
    float4 a = *(const float4*)(src + i * 8);
    float4 b = *(const float4*)(src + i * 8 + 4);
    u16x8 p;
    p[0]=f2bf(a.x); p[1]=f2bf(a.y); p[2]=f2bf(a.z); p[3]=f2bf(a.w);
    p[4]=f2bf(b.x); p[5]=f2bf(b.y); p[6]=f2bf(b.z); p[7]=f2bf(b.w);
    *(u16x8*)(dst + i * 8) = p;
  }
}

// ---------------- kernel 0b: bias table bf16 [16][49][52] (pad cols 49..51 = 0) ----------------
__global__ void build_bias_k(const float* __restrict__ rpb, unsigned short* __restrict__ biasT) {
  int idx = blockIdx.x * 256 + threadIdx.x;
  if (idx >= 16 * BSZ) return;
  int h = idx / BSZ;
  int rem = idx - h * BSZ;
  int i = rem / BSTRIDE, j = rem - (rem / BSTRIDE) * BSTRIDE;
  unsigned short v = 0;
  if (j < 49) {
    int r1 = i / 7, c1 = i - r1 * 7;
    int r2 = j / 7, c2 = j - r2 * 7;
    int ri = (r1 - r2 + 6) * 13 + (c1 - c2 + 6);
    v = f2bf(rpb[ri * 16 + h]);
  }
  biasT[idx] = v;
}

// Common staging/frag-read setup for the 128x128 BK=32 2-phase K-loop.
#define GEMM_SETUP(N0)                                                         \
  int t = threadIdx.x;                                                         \
  int lane = t & 63, wv = t >> 6;                                              \
  int g = lane >> 4, q = lane & 15;                                            \
  int wrow = wv >> 1, wcol = wv & 1;                                           \
  f32x4 acc[4][4] = {};                                                        \
  int schunk = (t & 3) ^ ((t >> 3) & 3);                                       \
  const unsigned short* ag0 = xb + (m0 + (t >> 2)) * 512 + schunk * 8;         \
  const unsigned short* ag1 = ag0 + 64 * 512;                                  \
  const unsigned short* bg0 = wb + (size_t)((N0) + (t >> 2)) * 512 + schunk * 8; \
  const unsigned short* bg1 = bg0 + 64 * 512;                                  \
  unsigned short* alA  = Ab + wv * 512;                                        \
  unsigned short* alA2 = Ab + 2048 + wv * 512;                                 \
  unsigned short* blB  = Bb + wv * 512;                                        \
  unsigned short* blB2 = Bb + 2048 + wv * 512;                                 \
  int roff = (8 * g) ^ (((q >> 1) & 3) << 3);                                  \
  const unsigned short* arb = Ab + (wrow * 64 + q) * 32 + roff;                \
  const unsigned short* brb = Bb + (wcol * 64 + q) * 32 + roff;

#define STAGE(KT, BOFF) do {                    \
    int kof = (KT) * 32;                        \
    gload_lds16(ag0 + kof, alA  + (BOFF));      \
    gload_lds16(ag1 + kof, alA2 + (BOFF));      \
    gload_lds16(bg0 + kof, blB  + (BOFF));      \
    gload_lds16(bg1 + kof, blB2 + (BOFF));      \
  } while (0)

// SWAPPED=0: acc[i2][j2] r -> m=wrow*64+i2*16+4g+r, n=wcol*64+j2*16+q  (V path)
// SWAPPED=1: acc[i2][j2] r -> n=wcol*64+j2*16+4g+r, m=wrow*64+i2*16+q  (Q/K path)
#define COMPUTE(BOFF, SWAPPED) do {                                            \
    bf16x8 af[4], bfr[4];                                                      \
    _Pragma("unroll")                                                          \
    for (int i2 = 0; i2 < 4; ++i2) af[i2]  = *(const bf16x8*)(arb + (BOFF) + i2 * 512); \
    _Pragma("unroll")                                                          \
    for (int j2 = 0; j2 < 4; ++j2) bfr[j2] = *(const bf16x8*)(brb + (BOFF) + j2 * 512); \
    _Pragma("unroll")                                                          \
    for (int i2 = 0; i2 < 4; ++i2)                                             \
      _Pragma("unroll")                                                        \
      for (int j2 = 0; j2 < 4; ++j2)                                           \
        acc[i2][j2] = (SWAPPED)                                                \
          ? __builtin_amdgcn_mfma_f32_16x16x32_bf16(bfr[j2], af[i2], acc[i2][j2], 0, 0, 0) \
          : __builtin_amdgcn_mfma_f32_16x16x32_bf16(af[i2], bfr[j2], acc[i2][j2], 0, 0, 0); \
  } while (0)

#define KLOOP(SWAPPED)                          \
  STAGE(0, 0);                                  \
  __syncthreads();                              \
  for (int kt = 0; kt < 16; kt += 2) {          \
    STAGE(kt + 1, 4096);                        \
    COMPUTE(0, SWAPPED);                        \
    __syncthreads();                            \
    if (kt + 2 < 16) STAGE(kt + 2, 0);          \
    COMPUTE(4096, SWAPPED);                     \
    __syncthreads();                            \
  }

// ---------------- kernel 1: combined QKV GEMM ----------------
// Single kernel (interleaved q/k/v writes in time -> attn inputs stay L3-hot),
// block-uniform branch on s: Q/K use swapped MFMA + direct packed stores (R8-proven),
// V uses normal orientation + packed VT stores (R6-proven).
__global__ __launch_bounds__(256, 4) void qkv_gemm_k(
    const unsigned short* __restrict__ xb, const float* __restrict__ qkv_b,
    const unsigned short* __restrict__ wb,
    unsigned short* __restrict__ qs, unsigned short* __restrict__ kk,
    unsigned short* __restrict__ vt)
{
  __shared__ __align__(16) unsigned short smem[16384];
  unsigned short* Ab = smem;          // [2][128][32]
  unsigned short* Bb = smem + 8192;

  int bid = blockIdx.x;
  int sw = (bid & 7) * 1176 + (bid >> 3);   // 9408 % 8 == 0 -> bijective
  int mt = sw / 12, nt = sw - mt * 12;      // 12 nt share one A panel (q,k,v interleaved)
  long m0 = (long)mt * 128;
  int  n0 = nt * 128;
  int  s  = n0 >> 9;                        // block-uniform: 0=Q, 1=K, 2=V

  GEMM_SETUP(n0)

  if (s < 2) {
    KLOOP(1)
    // epilogue: lane-local m = wrow*64+i2*16+q; 4 consecutive n = wcol*64+j2*16+4g+r
    unsigned short* dst = (s == 0) ? qs : kk;
    float sc = (s == 0) ? 0.17677669529663687f : 1.0f;
    float4 bi[4];
    int hj[4], dj[4];
    #pragma unroll
    for (int j2 = 0; j2 < 4; ++j2) {
      int n = n0 + wcol * 64 + j2 * 16 + 4 * g;
      bi[j2] = *(const float4*)(qkv_b + n);
      hj[j2] = (n >> 5) & 15;
      dj[j2] = n & 31;
    }
    #pragma unroll
    for (int i2 = 0; i2 < 4; ++i2) {
      unsigned int m = (unsigned int)m0 + wrow * 64 + i2 * 16 + q;
      unsigned int b = m / 49;
      unsigned int i = m - b * 49;
      size_t base = ((size_t)(b * 16) * 49 + i) * 32;
      #pragma unroll
      for (int j2 = 0; j2 < 4; ++j2) {
        f32x4 a = acc[i2][j2];
        unsigned int lo = (unsigned int)f2bf((a[0] + bi[j2].x) * sc) | ((unsigned int)f2bf((a[1] + bi[j2].y) * sc) << 16);
        unsigned int hi = (unsigned int)f2bf((a[2] + bi[j2].z) * sc) | ((unsigned int)f2bf((a[3] + bi[j2].w) * sc) << 16);
        u32x2 wv2 = {lo, hi};
        *(u32x2*)(dst + base + (size_t)hj[j2] * (49 * 32) + dj[j2]) = wv2;
      }
    }
  } else {
    KLOOP(0)
    // epilogue: thread's 4 r-values are consecutive i in VT -> packed dword stores
    #pragma unroll
    for (int j2 = 0; j2 < 4; ++j2) {
      int n  = n0 + wcol * 64 + j2 * 16 + q;
      float bias = qkv_b[n];
      int d = n & 31;
      int h = (n >> 5) & 15;
      #pragma unroll
      for (int i2 = 0; i2 < 4; ++i2) {
        unsigned int gm0 = (unsigned int)m0 + wrow * 64 + i2 * 16 + 4 * g;
        unsigned int b0 = gm0 / 49;
        unsigned int i0 = gm0 - b0 * 49;
        unsigned short hv[4];
        #pragma unroll
        for (int r = 0; r < 4; ++r) hv[r] = f2bf(acc[i2][j2][r] + bias);
        if (i0 <= 45) {
          unsigned short* base = vt + ((size_t)(b0 * 16 + h) * 32 + d) * VT_LD;
          if ((i0 & 1) == 0) {
            *(unsigned int*)(base + i0)     = (unsigned int)hv[0] | ((unsigned int)hv[1] << 16);
            *(unsigned int*)(base + i0 + 2) = (unsigned int)hv[2] | ((unsigned int)hv[3] << 16);
          } else {
            base[i0] = hv[0];
            *(unsigned int*)(base + i0 + 1) = (unsigned int)hv[1] | ((unsigned int)hv[2] << 16);
            base[i0 + 3] = hv[3];
          }
        } else {
          #pragma unroll
          for (int r = 0; r < 4; ++r) {
            unsigned int gm = gm0 + r;
            unsigned int b = gm / 49;
            unsigned int i = gm - b * 49;
            vt[((size_t)(b * 16 + h) * 32 + d) * VT_LD + i] = hv[r];
          }
        }
      }
    }
  }
}

// ---------------- kernel 2: fused window attention (R6-verbatim, 124 µs config) ----------------
__global__ __launch_bounds__(256, 2) void win_attn_k(
    const unsigned short* __restrict__ qs, const unsigned short* __restrict__ kk,
    const unsigned short* __restrict__ vt, const unsigned short* __restrict__ biasT,
    const float* __restrict__ mask, float* __restrict__ out)
{
  __shared__ float mlds[BSZ];                    // mask, stride-52 rows, pad cols = 0
  __shared__ unsigned short plds[4][64 * PLD];   // per-wave P

  int b = blockIdx.x;
  int t = threadIdx.x;
  int lane = t & 63, wv = t >> 6;
  int g = lane >> 4, q = lane & 15;

  const float* msrc = mask + (size_t)(b & 63) * 2401;
  for (int idx = t; idx < BSZ; idx += 256) {
    int i = idx / BSTRIDE, j = idx - (idx / BSTRIDE) * BSTRIDE;
    mlds[idx] = (j < 49) ? msrc[i * 49 + j] : 0.0f;
  }
  __syncthreads();

  unsigned short* pl = plds[wv];
  const float NINF = -__builtin_inff();

  int rc[4];
  rc[0] = q; rc[1] = 16 + q; rc[2] = 32 + q; rc[3] = 48;

  int h0 = wv * 4;
  const unsigned short* qh = qs + (size_t)(b * 16 + h0) * (49 * 32);
  const unsigned short* kh = kk + (size_t)(b * 16 + h0) * (49 * 32);
  bf16x8 ak[4], bq[4];
  #pragma unroll
  for (int jt = 0; jt < 4; ++jt) ak[jt] = *(const bf16x8*)(kh + rc[jt] * 32 + 8 * g);
  #pragma unroll
  for (int it = 0; it < 4; ++it) bq[it] = *(const bf16x8*)(qh + rc[it] * 32 + 8 * g);

  #pragma unroll
  for (int hh = 0; hh < 4; ++hh) {
    int h = wv * 4 + hh;
    const unsigned short* vh  = vt + (size_t)(b * 16 + h) * (32 * VT_LD);
    const unsigned short* bh2 = biasT + h * BSZ;

    f32x4 zero = {0.f, 0.f, 0.f, 0.f};
    f32x4 st[4][4];
    __builtin_amdgcn_s_setprio(1);
    #pragma unroll
    for (int it = 0; it < 4; ++it)
      #pragma unroll
      for (int jt = 0; jt < 4; ++jt)
        st[it][jt] = __builtin_amdgcn_mfma_f32_16x16x32_bf16(ak[jt], bq[it], zero, 0, 0, 0);
    __builtin_amdgcn_s_setprio(0);

    bf16x8 akn[4], bqn[4];
    if (hh < 3) {
      const unsigned short* qh2 = qh + 49 * 32;
      const unsigned short* kh2 = kh + 49 * 32;
      #pragma unroll
      for (int jt = 0; jt < 4; ++jt) akn[jt] = *(const bf16x8*)(kh2 + rc[jt] * 32 + 8 * g);
      #pragma unroll
      for (int it = 0; it < 4; ++it) bqn[it] = *(const bf16x8*)(qh2 + rc[it] * 32 + 8 * g);
      qh = qh2; kh = kh2;
    }
    bf16x8 bv[2][2];
    #pragma unroll
    for (int ktt = 0; ktt < 2; ++ktt)
      #pragma unroll
      for (int dt = 0; dt < 2; ++dt)
        bv[ktt][dt] = *(const bf16x8*)(vh + (dt * 16 + q) * VT_LD + ktt * 32 + 8 * g);

    #pragma unroll
    for (int it = 0; it < 4; ++it) {
      int i = it * 16 + q;
      int ic = i > 48 ? 48 : i;
      f32x4 pv4[4];
      f32x4 vm = {NINF, NINF, NINF, NINF};
      #pragma unroll
      for (int jt = 0; jt < 4; ++jt) {
        if (jt == 3 && g > 0) {
          pv4[3] = (f32x4){NINF, NINF, NINF, NINF};
        } else {
          u16x4 bu = *(const u16x4*)(bh2 + ic * BSTRIDE + jt * 16 + 4 * g);
          f32x4 m4 = *(const f32x4*)(mlds + ic * BSTRIDE + jt * 16 + 4 * g);
          f32x4 sv = st[it][jt];
          #pragma unroll
          for (int r = 0; r < 4; ++r) sv[r] += bf2f(bu[r]) + m4[r];
          if (jt == 3) {            // g==0 here: j = 48+r, valid only r==0
            sv[1] = NINF; sv[2] = NINF; sv[3] = NINF;
          }
          pv4[jt] = sv;
          #pragma unroll
          for (int r = 0; r < 4; ++r) vm[r] = fmaxf(vm[r], sv[r]);
        }
      }
      float mx = fmaxf(fmaxf(vm[0], vm[1]), fmaxf(vm[2], vm[3]));
      mx = fmaxf(mx, __shfl_xor(mx, 16));
      mx = fmaxf(mx, __shfl_xor(mx, 32));
      f32x4 vs = zero;
      #pragma unroll
      for (int jt = 0; jt < 4; ++jt) {
        #pragma unroll
        for (int r = 0; r < 4; ++r) {
          float p = __expf(pv4[jt][r] - mx);
          pv4[jt][r] = p;
          vs[r] += p;
        }
      }
      float sm = (vs[0] + vs[1]) + (vs[2] + vs[3]);
      sm += __shfl_xor(sm, 16);
      sm += __shfl_xor(sm, 32);
      float rv = 1.0f / sm;
      #pragma unroll
      for (int jt = 0; jt < 4; ++jt) {
        unsigned int lo = (unsigned int)f2bf(pv4[jt][0] * rv) | ((unsigned int)f2bf(pv4[jt][1] * rv) << 16);
        unsigned int hi = (unsigned int)f2bf(pv4[jt][2] * rv) | ((unsigned int)f2bf(pv4[jt][3] * rv) << 16);
        u32x2 w = {lo, hi};
        *(u32x2*)(pl + i * PLD + jt * 16 + 4 * g) = w;
      }
    }

    f32x4 oacc[4][2] = {};
    #pragma unroll
    for (int ktt = 0; ktt < 2; ++ktt) {
      bf16x8 pa[4];
      #pragma unroll
      for (int it = 0; it < 4; ++it)
        pa[it] = *(const bf16x8*)(pl + (it * 16 + q) * PLD + ktt * 32 + 8 * g);
      __builtin_amdgcn_s_setprio(1);
      #pragma unroll
      for (int it = 0; it < 4; ++it)
        #pragma unroll
        for (int dt = 0; dt < 2; ++dt)
          oacc[it][dt] = __builtin_amdgcn_mfma_f32_16x16x32_bf16(pa[it], bv[ktt][dt], oacc[it][dt], 0, 0, 0);
      __builtin_amdgcn_s_setprio(0);
    }

    #pragma unroll
    for (int it = 0; it < 4; ++it) {
      #pragma unroll
      for (int dt = 0; dt < 2; ++dt) {
        #pragma unroll
        for (int r = 0; r < 4; ++r) {
          int i = it * 16 + 4 * g + r;
          if (i < 49) {
            int d = dt * 16 + q;
            out[(size_t)(b * 49 + i) * 512 + h * 32 + d] = oacc[it][dt][r];
          }
        }
      }
    }

    if (hh < 3) {
      #pragma unroll
      for (int jt = 0; jt < 4; ++jt) ak[jt] = akn[jt];
      #pragma unroll
      for (int it = 0; it < 4; ++it) bq[it] = bqn[it];
    }
  }
}

// ---------------- launcher ----------------
extern "C" void kernel_launch(void* const* d_in, const int* in_sizes, int n_in,
                              void* d_out, int out_size, void* d_ws, size_t ws_size,
                              hipStream_t stream) {
  const float* x     = (const float*)d_in[0];
  const float* mask  = (const float*)d_in[1];
  const float* qkv_w = (const float*)d_in[2];
  const float* qkv_b = (const float*)d_in[3];
  const float* rpb   = (const float*)d_in[4];
  float* out = (float*)d_out;

  // workspace layout (bytes)
  const size_t QS_OFF   = 0;                         // 2048*16*49*32*2 = 102,760,448
  const size_t KK_OFF   = 102760448;
  const size_t VT_OFF   = 205520896;                 // 2048*16*32*56*2 = 117,440,512
  const size_t BIAS_OFF = 322961408;                 // 16*2548*2      = 81,536
  const size_t WB_OFF   = 323042944;                 // 1536*512*2     = 1,572,864
  const size_t NEED     = 324615808;
  if (ws_size < NEED) return;

  char* ws = (char*)d_ws;
  unsigned short* qsb   = (unsigned short*)(ws + QS_OFF);
  unsigned short* kkb   = (unsigned short*)(ws + KK_OFF);
  unsigned short* vtb   = (unsigned short*)(ws + VT_OFF);
  unsigned short* biasT = (unsigned short*)(ws + BIAS_OFF);
  unsigned short* wb    = (unsigned short*)(ws + WB_OFF);

  // xb (bf16 x, 103 MB) lives in d_out (205 MB fp32) — dead until win_attn
  // fully overwrites it.
  unsigned short* xb = (unsigned short*)d_out;

  conv_f2b_k<<<2048, 256, 0, stream>>>(x, xb, 6422528);        // 100352*512/8
  conv_f2b_k<<<512, 256, 0, stream>>>(qkv_w, wb, 98304);       // 1536*512/8
  build_bias_k<<<160, 256, 0, stream>>>(rpb, biasT);           // 16*2548
  qkv_gemm_k<<<9408, 256, 0, stream>>>(xb, qkv_b, wb, qsb, kkb, vtb);
  win_attn_k<<<2048, 256, 0, stream>>>(qsb, kkb, vtb, biasT, mask, out);
}

// Round 12
// 449.614 us; speedup vs baseline: 1.2036x; 1.0190x over previous
//
#include <hip/hip_runtime.h>
#include <cstdint>
#include <cstddef>

typedef __bf16 bf16x8 __attribute__((ext_vector_type(8)));
typedef float f32x4 __attribute__((ext_vector_type(4)));
typedef unsigned short u16x8 __attribute__((ext_vector_type(8)));
typedef unsigned short u16x4 __attribute__((ext_vector_type(4)));
typedef unsigned int u32x2 __attribute__((ext_vector_type(2)));

#define VT_LD 56   // padded j-stride of V^T rows
#define BSTRIDE 52 // bias/mask row stride (elements)
#define BSZ 2548   // 49*52 per head
#define PLD 80     // P LDS row stride (shorts) — R6-proven config

__device__ __forceinline__ unsigned short f2bf(float f) {
  unsigned int u = __builtin_bit_cast(unsigned int, f);
  u += 0x7FFFu + ((u >> 16) & 1u);   // RNE
  return (unsigned short)(u >> 16);
}
__device__ __forceinline__ float bf2f(unsigned short h) {
  unsigned int u = (unsigned int)h << 16;
  return __builtin_bit_cast(float, u);
}

__device__ __forceinline__ void gload_lds16(const void* g, void* l) {
  __builtin_amdgcn_global_load_lds((const __attribute__((address_space(1))) void*)g,
                                   (__attribute__((address_space(3))) void*)l, 16, 0, 0);
}

// ---------------- kernel 0: generic fp32 -> bf16 (vec8, grid-stride) ----------------
__global__ void conv_f2b_k(const float* __restrict__ src, unsigned short* __restrict__ dst, long n8) {
  long i = (long)blockIdx.x * blockDim.x + threadIdx.x;
  long stride = (long)gridDim.x * blockDim.x;
  for (; i < n8; i += stride) {
    float4 a = *(const float4*)(src + i * 8);
    float4 b = *(const float4*)(src + i * 8 + 4);
    u16x8 p;
    p[0]=f2bf(a.x); p[1]=f2bf(a.y); p[2]=f2bf(a.z); p[3]=f2bf(a.w);
    p[4]=f2bf(b.x); p[5]=f2bf(b.y); p[6]=f2bf(b.z); p[7]=f2bf(b.w);
    *(u16x8*)(dst + i * 8) = p;
  }
}

// ---------------- kernel 0b: bias table bf16 [16][49][52] (pad cols 49..51 = 0) ----------------
__global__ void build_bias_k(const float* __restrict__ rpb, unsigned short* __restrict__ biasT) {
  int idx = blockIdx.x * 256 + threadIdx.x;
  if (idx >= 16 * BSZ) return;
  int h = idx / BSZ;
  int rem = idx - h * BSZ;
  int i = rem / BSTRIDE, j = rem - (rem / BSTRIDE) * BSTRIDE;
  unsigned short v = 0;
  if (j < 49) {
    int r1 = i / 7, c1 = i - r1 * 7;
    int r2 = j / 7, c2 = j - r2 * 7;
    int ri = (r1 - r2 + 6) * 13 + (c1 - c2 + 6);
    v = f2bf(rpb[ri * 16 + h]);
  }
  biasT[idx] = v;
}

// Common staging/frag-read setup for the 128x128 BK=32 2-phase K-loop.
#define GEMM_SETUP(N0)                                                         \
  int t = threadIdx.x;                                                         \
  int lane = t & 63, wv = t >> 6;                                              \
  int g = lane >> 4, q = lane & 15;                                            \
  int wrow = wv >> 1, wcol = wv & 1;                                           \
  f32x4 acc[4][4] = {};                                                        \
  int schunk = (t & 3) ^ ((t >> 3) & 3);                                       \
  const unsigned short* ag0 = xb + (m0 + (t >> 2)) * 512 + schunk * 8;         \
  const unsigned short* ag1 = ag0 + 64 * 512;                                  \
  const unsigned short* bg0 = wb + (size_t)((N0) + (t >> 2)) * 512 + schunk * 8; \
  const unsigned short* bg1 = bg0 + 64 * 512;                                  \
  unsigned short* alA  = Ab + wv * 512;                                        \
  unsigned short* alA2 = Ab + 2048 + wv * 512;                                 \
  unsigned short* blB  = Bb + wv * 512;                                        \
  unsigned short* blB2 = Bb + 2048 + wv * 512;                                 \
  int roff = (8 * g) ^ (((q >> 1) & 3) << 3);                                  \
  const unsigned short* arb = Ab + (wrow * 64 + q) * 32 + roff;                \
  const unsigned short* brb = Bb + (wcol * 64 + q) * 32 + roff;

#define STAGE(KT, BOFF) do {                    \
    int kof = (KT) * 32;                        \
    gload_lds16(ag0 + kof, alA  + (BOFF));      \
    gload_lds16(ag1 + kof, alA2 + (BOFF));      \
    gload_lds16(bg0 + kof, blB  + (BOFF));      \
    gload_lds16(bg1 + kof, blB2 + (BOFF));      \
  } while (0)

// SWAPPED=0: acc[i2][j2] r -> m=wrow*64+i2*16+4g+r, n=wcol*64+j2*16+q  (V path)
// SWAPPED=1: acc[i2][j2] r -> n=wcol*64+j2*16+4g+r, m=wrow*64+i2*16+q  (Q/K path)
#define COMPUTE(BOFF, SWAPPED) do {                                            \
    bf16x8 af[4], bfr[4];                                                      \
    _Pragma("unroll")                                                          \
    for (int i2 = 0; i2 < 4; ++i2) af[i2]  = *(const bf16x8*)(arb + (BOFF) + i2 * 512); \
    _Pragma("unroll")                                                          \
    for (int j2 = 0; j2 < 4; ++j2) bfr[j2] = *(const bf16x8*)(brb + (BOFF) + j2 * 512); \
    _Pragma("unroll")                                                          \
    for (int i2 = 0; i2 < 4; ++i2)                                             \
      _Pragma("unroll")                                                        \
      for (int j2 = 0; j2 < 4; ++j2)                                           \
        acc[i2][j2] = (SWAPPED)                                                \
          ? __builtin_amdgcn_mfma_f32_16x16x32_bf16(bfr[j2], af[i2], acc[i2][j2], 0, 0, 0) \
          : __builtin_amdgcn_mfma_f32_16x16x32_bf16(af[i2], bfr[j2], acc[i2][j2], 0, 0, 0); \
  } while (0)

#define KLOOP(SWAPPED)                          \
  STAGE(0, 0);                                  \
  __syncthreads();                              \
  for (int kt = 0; kt < 16; kt += 2) {          \
    STAGE(kt + 1, 4096);                        \
    COMPUTE(0, SWAPPED);                        \
    __syncthreads();                            \
    if (kt + 2 < 16) STAGE(kt + 2, 0);          \
    COMPUTE(4096, SWAPPED);                     \
    __syncthreads();                            \
  }

// ---------------- kernel 1: combined QKV GEMM ----------------
// Single kernel (interleaved q/k/v writes in time -> attn inputs stay L3-hot),
// block-uniform branch on s: Q/K use swapped MFMA + direct packed stores,
// V uses normal orientation + packed VT stores.
// bounds(256,3): (256,4) forced VGPR<=64 -> ~90 MB spill traffic (R11 counters).
__global__ __launch_bounds__(256, 3) void qkv_gemm_k(
    const unsigned short* __restrict__ xb, const float* __restrict__ qkv_b,
    const unsigned short* __restrict__ wb,
    unsigned short* __restrict__ qs, unsigned short* __restrict__ kk,
    unsigned short* __restrict__ vt)
{
  __shared__ __align__(16) unsigned short smem[16384];
  unsigned short* Ab = smem;          // [2][128][32]
  unsigned short* Bb = smem + 8192;

  int bid = blockIdx.x;
  int sw = (bid & 7) * 1176 + (bid >> 3);   // 9408 % 8 == 0 -> bijective
  int mt = sw / 12, nt = sw - mt * 12;      // 12 nt share one A panel (q,k,v interleaved)
  long m0 = (long)mt * 128;
  int  n0 = nt * 128;
  int  s  = n0 >> 9;                        // block-uniform: 0=Q, 1=K, 2=V

  GEMM_SETUP(n0)

  if (s < 2) {
    KLOOP(1)
    // epilogue: lane-local m = wrow*64+i2*16+q; 4 consecutive n = wcol*64+j2*16+4g+r
    unsigned short* dst = (s == 0) ? qs : kk;
    float sc = (s == 0) ? 0.17677669529663687f : 1.0f;
    float4 bi[4];
    int hj[4], dj[4];
    #pragma unroll
    for (int j2 = 0; j2 < 4; ++j2) {
      int n = n0 + wcol * 64 + j2 * 16 + 4 * g;
      bi[j2] = *(const float4*)(qkv_b + n);
      hj[j2] = (n >> 5) & 15;
      dj[j2] = n & 31;
    }
    #pragma unroll
    for (int i2 = 0; i2 < 4; ++i2) {
      unsigned int m = (unsigned int)m0 + wrow * 64 + i2 * 16 + q;
      unsigned int b = m / 49;
      unsigned int i = m - b * 49;
      size_t base = ((size_t)(b * 16) * 49 + i) * 32;
      #pragma unroll
      for (int j2 = 0; j2 < 4; ++j2) {
        f32x4 a = acc[i2][j2];
        unsigned int lo = (unsigned int)f2bf((a[0] + bi[j2].x) * sc) | ((unsigned int)f2bf((a[1] + bi[j2].y) * sc) << 16);
        unsigned int hi = (unsigned int)f2bf((a[2] + bi[j2].z) * sc) | ((unsigned int)f2bf((a[3] + bi[j2].w) * sc) << 16);
        u32x2 wv2 = {lo, hi};
        *(u32x2*)(dst + base + (size_t)hj[j2] * (49 * 32) + dj[j2]) = wv2;
      }
    }
  } else {
    KLOOP(0)
    // epilogue: thread's 4 r-values are consecutive i in VT -> packed dword stores
    #pragma unroll
    for (int j2 = 0; j2 < 4; ++j2) {
      int n  = n0 + wcol * 64 + j2 * 16 + q;
      float bias = qkv_b[n];
      int d = n & 31;
      int h = (n >> 5) & 15;
      #pragma unroll
      for (int i2 = 0; i2 < 4; ++i2) {
        unsigned int gm0 = (unsigned int)m0 + wrow * 64 + i2 * 16 + 4 * g;
        unsigned int b0 = gm0 / 49;
        unsigned int i0 = gm0 - b0 * 49;
        unsigned short hv[4];
        #pragma unroll
        for (int r = 0; r < 4; ++r) hv[r] = f2bf(acc[i2][j2][r] + bias);
        if (i0 <= 45) {
          unsigned short* base = vt + ((size_t)(b0 * 16 + h) * 32 + d) * VT_LD;
          if ((i0 & 1) == 0) {
            *(unsigned int*)(base + i0)     = (unsigned int)hv[0] | ((unsigned int)hv[1] << 16);
            *(unsigned int*)(base + i0 + 2) = (unsigned int)hv[2] | ((unsigned int)hv[3] << 16);
          } else {
            base[i0] = hv[0];
            *(unsigned int*)(base + i0 + 1) = (unsigned int)hv[1] | ((unsigned int)hv[2] << 16);
            base[i0 + 3] = hv[3];
          }
        } else {
          #pragma unroll
          for (int r = 0; r < 4; ++r) {
            unsigned int gm = gm0 + r;
            unsigned int b = gm / 49;
            unsigned int i = gm - b * 49;
            vt[((size_t)(b * 16 + h) * 32 + d) * VT_LD + i] = hv[r];
          }
        }
      }
    }
  }
}

// ---------------- kernel 2: fused window attention (R6-verbatim, 124 µs config) ----------------
__global__ __launch_bounds__(256, 2) void win_attn_k(
    const unsigned short* __restrict__ qs, const unsigned short* __restrict__ kk,
    const unsigned short* __restrict__ vt, const unsigned short* __restrict__ biasT,
    const float* __restrict__ mask, float* __restrict__ out)
{
  __shared__ float mlds[BSZ];                    // mask, stride-52 rows, pad cols = 0
  __shared__ unsigned short plds[4][64 * PLD];   // per-wave P

  int b = blockIdx.x;
  int t = threadIdx.x;
  int lane = t & 63, wv = t >> 6;
  int g = lane >> 4, q = lane & 15;

  const float* msrc = mask + (size_t)(b & 63) * 2401;
  for (int idx = t; idx < BSZ; idx += 256) {
    int i = idx / BSTRIDE, j = idx - (idx / BSTRIDE) * BSTRIDE;
    mlds[idx] = (j < 49) ? msrc[i * 49 + j] : 0.0f;
  }
  __syncthreads();

  unsigned short* pl = plds[wv];
  const float NINF = -__builtin_inff();

  int rc[4];
  rc[0] = q; rc[1] = 16 + q; rc[2] = 32 + q; rc[3] = 48;

  int h0 = wv * 4;
  const unsigned short* qh = qs + (size_t)(b * 16 + h0) * (49 * 32);
  const unsigned short* kh = kk + (size_t)(b * 16 + h0) * (49 * 32);
  bf16x8 ak[4], bq[4];
  #pragma unroll
  for (int jt = 0; jt < 4; ++jt) ak[jt] = *(const bf16x8*)(kh + rc[jt] * 32 + 8 * g);
  #pragma unroll
  for (int it = 0; it < 4; ++it) bq[it] = *(const bf16x8*)(qh + rc[it] * 32 + 8 * g);

  #pragma unroll
  for (int hh = 0; hh < 4; ++hh) {
    int h = wv * 4 + hh;
    const unsigned short* vh  = vt + (size_t)(b * 16 + h) * (32 * VT_LD);
    const unsigned short* bh2 = biasT + h * BSZ;

    f32x4 zero = {0.f, 0.f, 0.f, 0.f};
    f32x4 st[4][4];
    __builtin_amdgcn_s_setprio(1);
    #pragma unroll
    for (int it = 0; it < 4; ++it)
      #pragma unroll
      for (int jt = 0; jt < 4; ++jt)
        st[it][jt] = __builtin_amdgcn_mfma_f32_16x16x32_bf16(ak[jt], bq[it], zero, 0, 0, 0);
    __builtin_amdgcn_s_setprio(0);

    bf16x8 akn[4], bqn[4];
    if (hh < 3) {
      const unsigned short* qh2 = qh + 49 * 32;
      const unsigned short* kh2 = kh + 49 * 32;
      #pragma unroll
      for (int jt = 0; jt < 4; ++jt) akn[jt] = *(const bf16x8*)(kh2 + rc[jt] * 32 + 8 * g);
      #pragma unroll
      for (int it = 0; it < 4; ++it) bqn[it] = *(const bf16x8*)(qh2 + rc[it] * 32 + 8 * g);
      qh = qh2; kh = kh2;
    }
    bf16x8 bv[2][2];
    #pragma unroll
    for (int ktt = 0; ktt < 2; ++ktt)
      #pragma unroll
      for (int dt = 0; dt < 2; ++dt)
        bv[ktt][dt] = *(const bf16x8*)(vh + (dt * 16 + q) * VT_LD + ktt * 32 + 8 * g);

    #pragma unroll
    for (int it = 0; it < 4; ++it) {
      int i = it * 16 + q;
      int ic = i > 48 ? 48 : i;
      f32x4 pv4[4];
      f32x4 vm = {NINF, NINF, NINF, NINF};
      #pragma unroll
      for (int jt = 0; jt < 4; ++jt) {
        if (jt == 3 && g > 0) {
          pv4[3] = (f32x4){NINF, NINF, NINF, NINF};
        } else {
          u16x4 bu = *(const u16x4*)(bh2 + ic * BSTRIDE + jt * 16 + 4 * g);
          f32x4 m4 = *(const f32x4*)(mlds + ic * BSTRIDE + jt * 16 + 4 * g);
          f32x4 sv = st[it][jt];
          #pragma unroll
          for (int r = 0; r < 4; ++r) sv[r] += bf2f(bu[r]) + m4[r];
          if (jt == 3) {            // g==0 here: j = 48+r, valid only r==0
            sv[1] = NINF; sv[2] = NINF; sv[3] = NINF;
          }
          pv4[jt] = sv;
          #pragma unroll
          for (int r = 0; r < 4; ++r) vm[r] = fmaxf(vm[r], sv[r]);
        }
      }
      float mx = fmaxf(fmaxf(vm[0], vm[1]), fmaxf(vm[2], vm[3]));
      mx = fmaxf(mx, __shfl_xor(mx, 16));
      mx = fmaxf(mx, __shfl_xor(mx, 32));
      f32x4 vs = zero;
      #pragma unroll
      for (int jt = 0; jt < 4; ++jt) {
        #pragma unroll
        for (int r = 0; r < 4; ++r) {
          float p = __expf(pv4[jt][r] - mx);
          pv4[jt][r] = p;
          vs[r] += p;
        }
      }
      float sm = (vs[0] + vs[1]) + (vs[2] + vs[3]);
      sm += __shfl_xor(sm, 16);
      sm += __shfl_xor(sm, 32);
      float rv = 1.0f / sm;
      #pragma unroll
      for (int jt = 0; jt < 4; ++jt) {
        unsigned int lo = (unsigned int)f2bf(pv4[jt][0] * rv) | ((unsigned int)f2bf(pv4[jt][1] * rv) << 16);
        unsigned int hi = (unsigned int)f2bf(pv4[jt][2] * rv) | ((unsigned int)f2bf(pv4[jt][3] * rv) << 16);
        u32x2 w = {lo, hi};
        *(u32x2*)(pl + i * PLD + jt * 16 + 4 * g) = w;
      }
    }

    f32x4 oacc[4][2] = {};
    #pragma unroll
    for (int ktt = 0; ktt < 2; ++ktt) {
      bf16x8 pa[4];
      #pragma unroll
      for (int it = 0; it < 4; ++it)
        pa[it] = *(const bf16x8*)(pl + (it * 16 + q) * PLD + ktt * 32 + 8 * g);
      __builtin_amdgcn_s_setprio(1);
      #pragma unroll
      for (int it = 0; it < 4; ++it)
        #pragma unroll
        for (int dt = 0; dt < 2; ++dt)
          oacc[it][dt] = __builtin_amdgcn_mfma_f32_16x16x32_bf16(pa[it], bv[ktt][dt], oacc[it][dt], 0, 0, 0);
      __builtin_amdgcn_s_setprio(0);
    }

    #pragma unroll
    for (int it = 0; it < 4; ++it) {
      #pragma unroll
      for (int dt = 0; dt < 2; ++dt) {
        #pragma unroll
        for (int r = 0; r < 4; ++r) {
          int i = it * 16 + 4 * g + r;
          if (i < 49) {
            int d = dt * 16 + q;
            out[(size_t)(b * 49 + i) * 512 + h * 32 + d] = oacc[it][dt][r];
          }
        }
      }
    }

    if (hh < 3) {
      #pragma unroll
      for (int jt = 0; jt < 4; ++jt) ak[jt] = akn[jt];
      #pragma unroll
      for (int it = 0; it < 4; ++it) bq[it] = bqn[it];
    }
  }
}

// ---------------- launcher ----------------
extern "C" void kernel_launch(void* const* d_in, const int* in_sizes, int n_in,
                              void* d_out, int out_size, void* d_ws, size_t ws_size,
                              hipStream_t stream) {
  const float* x     = (const float*)d_in[0];
  const float* mask  = (const float*)d_in[1];
  const float* qkv_w = (const float*)d_in[2];
  const float* qkv_b = (const float*)d_in[3];
  const float* rpb   = (const float*)d_in[4];
  float* out = (float*)d_out;

  // workspace layout (bytes)
  const size_t QS_OFF   = 0;                         // 2048*16*49*32*2 = 102,760,448
  const size_t KK_OFF   = 102760448;
  const size_t VT_OFF   = 205520896;                 // 2048*16*32*56*2 = 117,440,512
  const size_t BIAS_OFF = 322961408;                 // 16*2548*2      = 81,536
  const size_t WB_OFF   = 323042944;                 // 1536*512*2     = 1,572,864
  const size_t NEED     = 324615808;
  if (ws_size < NEED) return;

  char* ws = (char*)d_ws;
  unsigned short* qsb   = (unsigned short*)(ws + QS_OFF);
  unsigned short* kkb   = (unsigned short*)(ws + KK_OFF);
  unsigned short* vtb   = (unsigned short*)(ws + VT_OFF);
  unsigned short* biasT = (unsigned short*)(ws + BIAS_OFF);
  unsigned short* wb    = (unsigned short*)(ws + WB_OFF);

  // xb (bf16 x, 103 MB) lives in d_out (205 MB fp32) — dead until win_attn
  // fully overwrites it.
  unsigned short* xb = (unsigned short*)d_out;

  conv_f2b_k<<<2048, 256, 0, stream>>>(x, xb, 6422528);        // 100352*512/8
  conv_f2b_k<<<512, 256, 0, stream>>>(qkv_w, wb, 98304);       // 1536*512/8
  build_bias_k<<<160, 256, 0, stream>>>(rpb, biasT);           // 16*2548
  qkv_gemm_k<<<9408, 256, 0, stream>>>(xb, qkv_b, wb, qsb, kkb, vtb);
  win_attn_k<<<2048, 256, 0, stream>>>(qsb, kkb, vtb, biasT, mask, out);
}

// Round 13
// 448.598 us; speedup vs baseline: 1.2063x; 1.0023x over previous
//
#include <hip/hip_runtime.h>
#include <cstdint>
#include <cstddef>

typedef __bf16 bf16x8 __attribute__((ext_vector_type(8)));
typedef float f32x4 __attribute__((ext_vector_type(4)));
typedef unsigned short u16x8 __attribute__((ext_vector_type(8)));
typedef unsigned short u16x4 __attribute__((ext_vector_type(4)));
typedef unsigned int u32x2 __attribute__((ext_vector_type(2)));

#define VT_LD 56   // padded j-stride of V^T rows
#define BSTRIDE 52 // bias/mask row stride (elements)
#define BSZ 2548   // 49*52 per head
#define PLD 80     // P LDS row stride (shorts)

__device__ __forceinline__ unsigned short f2bf(float f) {
  unsigned int u = __builtin_bit_cast(unsigned int, f);
  u += 0x7FFFu + ((u >> 16) & 1u);   // RNE
  return (unsigned short)(u >> 16);
}
__device__ __forceinline__ float bf2f(unsigned short h) {
  unsigned int u = (unsigned int)h << 16;
  return __builtin_bit_cast(float, u);
}

__device__ __forceinline__ void gload_lds16(const void* g, void* l) {
  __builtin_amdgcn_global_load_lds((const __attribute__((address_space(1))) void*)g,
                                   (__attribute__((address_space(3))) void*)l, 16, 0, 0);
}

// ---------------- kernel 0: generic fp32 -> bf16 (vec8, grid-stride) ----------------
__global__ void conv_f2b_k(const float* __restrict__ src, unsigned short* __restrict__ dst, long n8) {
  long i = (long)blockIdx.x * blockDim.x + threadIdx.x;
  long stride = (long)gridDim.x * blockDim.x;
  for (; i < n8; i += stride) {
    float4 a = *(const float4*)(src + i * 8);
    float4 b = *(const float4*)(src + i * 8 + 4);
    u16x8 p;
    p[0]=f2bf(a.x); p[1]=f2bf(a.y); p[2]=f2bf(a.z); p[3]=f2bf(a.w);
    p[4]=f2bf(b.x); p[5]=f2bf(b.y); p[6]=f2bf(b.z); p[7]=f2bf(b.w);
    *(u16x8*)(dst + i * 8) = p;
  }
}

// ---------------- kernel 0b: bias table bf16 [16][49][52] (pad cols 49..51 = 0) ----------------
__global__ void build_bias_k(const float* __restrict__ rpb, unsigned short* __restrict__ biasT) {
  int idx = blockIdx.x * 256 + threadIdx.x;
  if (idx >= 16 * BSZ) return;
  int h = idx / BSZ;
  int rem = idx - h * BSZ;
  int i = rem / BSTRIDE, j = rem - (rem / BSTRIDE) * BSTRIDE;
  unsigned short v = 0;
  if (j < 49) {
    int r1 = i / 7, c1 = i - r1 * 7;
    int r2 = j / 7, c2 = j - r2 * 7;
    int ri = (r1 - r2 + 6) * 13 + (c1 - c2 + 6);
    v = f2bf(rpb[ri * 16 + h]);
  }
  biasT[idx] = v;
}

// Common staging/frag-read setup for the 128x128 BK=32 K-loop (3-buffer pipelined).
#define GEMM_SETUP(N0)                                                         \
  int t = threadIdx.x;                                                         \
  int lane = t & 63, wv = t >> 6;                                              \
  int g = lane >> 4, q = lane & 15;                                            \
  int wrow = wv >> 1, wcol = wv & 1;                                           \
  f32x4 acc[4][4] = {};                                                        \
  int schunk = (t & 3) ^ ((t >> 3) & 3);                                       \
  const unsigned short* ag0 = xb + (m0 + (t >> 2)) * 512 + schunk * 8;         \
  const unsigned short* ag1 = ag0 + 64 * 512;                                  \
  const unsigned short* bg0 = wb + (size_t)((N0) + (t >> 2)) * 512 + schunk * 8; \
  const unsigned short* bg1 = bg0 + 64 * 512;                                  \
  unsigned short* alA  = Ab + wv * 512;                                        \
  unsigned short* alA2 = Ab + 2048 + wv * 512;                                 \
  unsigned short* blB  = Bb + wv * 512;                                        \
  unsigned short* blB2 = Bb + 2048 + wv * 512;                                 \
  int roff = (8 * g) ^ (((q >> 1) & 3) << 3);                                  \
  const unsigned short* arb = Ab + (wrow * 64 + q) * 32 + roff;                \
  const unsigned short* brb = Bb + (wcol * 64 + q) * 32 + roff;

#define STAGE(KT, BOFF) do {                    \
    int kof = (KT) * 32;                        \
    gload_lds16(ag0 + kof, alA  + (BOFF));      \
    gload_lds16(ag1 + kof, alA2 + (BOFF));      \
    gload_lds16(bg0 + kof, blB  + (BOFF));      \
    gload_lds16(bg1 + kof, blB2 + (BOFF));      \
  } while (0)

// SWAPPED=0: acc[i2][j2] r -> m=wrow*64+i2*16+4g+r, n=wcol*64+j2*16+q  (V path)
// SWAPPED=1: acc[i2][j2] r -> n=wcol*64+j2*16+4g+r, m=wrow*64+i2*16+q  (Q/K path)
#define COMPUTE(BOFF, SWAPPED) do {                                            \
    bf16x8 af[4], bfr[4];                                                      \
    _Pragma("unroll")                                                          \
    for (int i2 = 0; i2 < 4; ++i2) af[i2]  = *(const bf16x8*)(arb + (BOFF) + i2 * 512); \
    _Pragma("unroll")                                                          \
    for (int j2 = 0; j2 < 4; ++j2) bfr[j2] = *(const bf16x8*)(brb + (BOFF) + j2 * 512); \
    _Pragma("unroll")                                                          \
    for (int i2 = 0; i2 < 4; ++i2)                                             \
      _Pragma("unroll")                                                        \
      for (int j2 = 0; j2 < 4; ++j2)                                           \
        acc[i2][j2] = (SWAPPED)                                                \
          ? __builtin_amdgcn_mfma_f32_16x16x32_bf16(bfr[j2], af[i2], acc[i2][j2], 0, 0, 0) \
          : __builtin_amdgcn_mfma_f32_16x16x32_bf16(af[i2], bfr[j2], acc[i2][j2], 0, 0, 0); \
  } while (0)

// 3-buffer pipeline, counted vmcnt (T4): tile t+1's loads stay in flight across
// the barrier; only the oldest tile is waited. N = 4 loads/tile in flight.
// WAR-safe: buffer staged at iter t was read at iter t-1; those ds_reads are
// consumed by MFMAs before that iter's barrier (m201-template argument).
#define KLOOP(SWAPPED)                                                 \
  STAGE(0, 0);                                                         \
  STAGE(1, 4096);                                                      \
  asm volatile("s_waitcnt vmcnt(4)" ::: "memory");                     \
  __builtin_amdgcn_s_barrier();                                        \
  _Pragma("unroll")                                                    \
  for (int kt = 0; kt < 16; ++kt) {                                    \
    if (kt + 2 < 16) STAGE(kt + 2, ((kt + 2) % 3) * 4096);             \
    COMPUTE((kt % 3) * 4096, SWAPPED);                                 \
    if (kt < 15) {                                                     \
      if (kt + 2 < 16) asm volatile("s_waitcnt vmcnt(4)" ::: "memory"); \
      else             asm volatile("s_waitcnt vmcnt(0)" ::: "memory"); \
      __builtin_amdgcn_s_barrier();                                    \
    }                                                                  \
  }

// ---------------- kernel 1: combined QKV GEMM ----------------
__global__ __launch_bounds__(256, 3) void qkv_gemm_k(
    const unsigned short* __restrict__ xb, const float* __restrict__ qkv_b,
    const unsigned short* __restrict__ wb,
    unsigned short* __restrict__ qs, unsigned short* __restrict__ kk,
    unsigned short* __restrict__ vt)
{
  __shared__ __align__(16) unsigned short smem[24576];   // A: 3x4096, B: 3x4096
  unsigned short* Ab = smem;
  unsigned short* Bb = smem + 12288;

  int bid = blockIdx.x;
  int sw = (bid & 7) * 1176 + (bid >> 3);   // 9408 % 8 == 0 -> bijective
  int mt = sw / 12, nt = sw - mt * 12;      // 12 nt share one A panel (q,k,v interleaved)
  long m0 = (long)mt * 128;
  int  n0 = nt * 128;
  int  s  = n0 >> 9;                        // block-uniform: 0=Q, 1=K, 2=V

  GEMM_SETUP(n0)

  if (s < 2) {
    KLOOP(1)
    // epilogue: lane-local m = wrow*64+i2*16+q; 4 consecutive n = wcol*64+j2*16+4g+r
    unsigned short* dst = (s == 0) ? qs : kk;
    float sc = (s == 0) ? 0.17677669529663687f : 1.0f;
    float4 bi[4];
    int hj[4], dj[4];
    #pragma unroll
    for (int j2 = 0; j2 < 4; ++j2) {
      int n = n0 + wcol * 64 + j2 * 16 + 4 * g;
      bi[j2] = *(const float4*)(qkv_b + n);
      hj[j2] = (n >> 5) & 15;
      dj[j2] = n & 31;
    }
    #pragma unroll
    for (int i2 = 0; i2 < 4; ++i2) {
      unsigned int m = (unsigned int)m0 + wrow * 64 + i2 * 16 + q;
      unsigned int b = m / 49;
      unsigned int i = m - b * 49;
      size_t base = ((size_t)(b * 16) * 49 + i) * 32;
      #pragma unroll
      for (int j2 = 0; j2 < 4; ++j2) {
        f32x4 a = acc[i2][j2];
        unsigned int lo = (unsigned int)f2bf((a[0] + bi[j2].x) * sc) | ((unsigned int)f2bf((a[1] + bi[j2].y) * sc) << 16);
        unsigned int hi = (unsigned int)f2bf((a[2] + bi[j2].z) * sc) | ((unsigned int)f2bf((a[3] + bi[j2].w) * sc) << 16);
        u32x2 wv2 = {lo, hi};
        *(u32x2*)(dst + base + (size_t)hj[j2] * (49 * 32) + dj[j2]) = wv2;
      }
    }
  } else {
    KLOOP(0)
    // epilogue: thread's 4 r-values are consecutive i in VT -> packed dword stores
    #pragma unroll
    for (int j2 = 0; j2 < 4; ++j2) {
      int n  = n0 + wcol * 64 + j2 * 16 + q;
      float bias = qkv_b[n];
      int d = n & 31;
      int h = (n >> 5) & 15;
      #pragma unroll
      for (int i2 = 0; i2 < 4; ++i2) {
        unsigned int gm0 = (unsigned int)m0 + wrow * 64 + i2 * 16 + 4 * g;
        unsigned int b0 = gm0 / 49;
        unsigned int i0 = gm0 - b0 * 49;
        unsigned short hv[4];
        #pragma unroll
        for (int r = 0; r < 4; ++r) hv[r] = f2bf(acc[i2][j2][r] + bias);
        if (i0 <= 45) {
          unsigned short* base = vt + ((size_t)(b0 * 16 + h) * 32 + d) * VT_LD;
          if ((i0 & 1) == 0) {
            *(unsigned int*)(base + i0)     = (unsigned int)hv[0] | ((unsigned int)hv[1] << 16);
            *(unsigned int*)(base + i0 + 2) = (unsigned int)hv[2] | ((unsigned int)hv[3] << 16);
          } else {
            base[i0] = hv[0];
            *(unsigned int*)(base + i0 + 1) = (unsigned int)hv[1] | ((unsigned int)hv[2] << 16);
            base[i0 + 3] = hv[3];
          }
        } else {
          #pragma unroll
          for (int r = 0; r < 4; ++r) {
            unsigned int gm = gm0 + r;
            unsigned int b = gm / 49;
            unsigned int i = gm - b * 49;
            vt[((size_t)(b * 16 + h) * 32 + d) * VT_LD + i] = hv[r];
          }
        }
      }
    }
  }
}

// ---------------- kernel 2: fused window attention ----------------
// swapped QK^T (rows lane-local) + swapped PV (d lane-local -> float4 stores)
__global__ __launch_bounds__(256, 2) void win_attn_k(
    const unsigned short* __restrict__ qs, const unsigned short* __restrict__ kk,
    const unsigned short* __restrict__ vt, const unsigned short* __restrict__ biasT,
    const float* __restrict__ mask, float* __restrict__ out)
{
  __shared__ float mlds[BSZ];                    // mask, stride-52 rows, pad cols = 0
  __shared__ unsigned short plds[4][64 * PLD];   // per-wave P

  int b = blockIdx.x;
  int t = threadIdx.x;
  int lane = t & 63, wv = t >> 6;
  int g = lane >> 4, q = lane & 15;

  const float* msrc = mask + (size_t)(b & 63) * 2401;
  for (int idx = t; idx < BSZ; idx += 256) {
    int i = idx / BSTRIDE, j = idx - (idx / BSTRIDE) * BSTRIDE;
    mlds[idx] = (j < 49) ? msrc[i * 49 + j] : 0.0f;
  }
  __syncthreads();

  unsigned short* pl = plds[wv];
  const float NINF = -__builtin_inff();

  int rc[4];
  rc[0] = q; rc[1] = 16 + q; rc[2] = 32 + q; rc[3] = 48;

  int h0 = wv * 4;
  const unsigned short* qh = qs + (size_t)(b * 16 + h0) * (49 * 32);
  const unsigned short* kh = kk + (size_t)(b * 16 + h0) * (49 * 32);
  bf16x8 ak[4], bq[4];
  #pragma unroll
  for (int jt = 0; jt < 4; ++jt) ak[jt] = *(const bf16x8*)(kh + rc[jt] * 32 + 8 * g);
  #pragma unroll
  for (int it = 0; it < 4; ++it) bq[it] = *(const bf16x8*)(qh + rc[it] * 32 + 8 * g);

  #pragma unroll
  for (int hh = 0; hh < 4; ++hh) {
    int h = wv * 4 + hh;
    const unsigned short* vh  = vt + (size_t)(b * 16 + h) * (32 * VT_LD);
    const unsigned short* bh2 = biasT + h * BSZ;

    f32x4 zero = {0.f, 0.f, 0.f, 0.f};
    f32x4 st[4][4];
    __builtin_amdgcn_s_setprio(1);
    #pragma unroll
    for (int it = 0; it < 4; ++it)
      #pragma unroll
      for (int jt = 0; jt < 4; ++jt)
        st[it][jt] = __builtin_amdgcn_mfma_f32_16x16x32_bf16(ak[jt], bq[it], zero, 0, 0, 0);
    __builtin_amdgcn_s_setprio(0);

    bf16x8 akn[4], bqn[4];
    if (hh < 3) {
      const unsigned short* qh2 = qh + 49 * 32;
      const unsigned short* kh2 = kh + 49 * 32;
      #pragma unroll
      for (int jt = 0; jt < 4; ++jt) akn[jt] = *(const bf16x8*)(kh2 + rc[jt] * 32 + 8 * g);
      #pragma unroll
      for (int it = 0; it < 4; ++it) bqn[it] = *(const bf16x8*)(qh2 + rc[it] * 32 + 8 * g);
      qh = qh2; kh = kh2;
    }
    bf16x8 bv[2][2];
    #pragma unroll
    for (int ktt = 0; ktt < 2; ++ktt)
      #pragma unroll
      for (int dt = 0; dt < 2; ++dt)
        bv[ktt][dt] = *(const bf16x8*)(vh + (dt * 16 + q) * VT_LD + ktt * 32 + 8 * g);

    #pragma unroll
    for (int it = 0; it < 4; ++it) {
      int i = it * 16 + q;
      int ic = i > 48 ? 48 : i;
      f32x4 pv4[4];
      f32x4 vm = {NINF, NINF, NINF, NINF};
      #pragma unroll
      for (int jt = 0; jt < 4; ++jt) {
        if (jt == 3 && g > 0) {
          pv4[3] = (f32x4){NINF, NINF, NINF, NINF};
        } else {
          u16x4 bu = *(const u16x4*)(bh2 + ic * BSTRIDE + jt * 16 + 4 * g);
          f32x4 m4 = *(const f32x4*)(mlds + ic * BSTRIDE + jt * 16 + 4 * g);
          f32x4 sv = st[it][jt];
          #pragma unroll
          for (int r = 0; r < 4; ++r) sv[r] += bf2f(bu[r]) + m4[r];
          if (jt == 3) {            // g==0 here: j = 48+r, valid only r==0
            sv[1] = NINF; sv[2] = NINF; sv[3] = NINF;
          }
          pv4[jt] = sv;
          #pragma unroll
          for (int r = 0; r < 4; ++r) vm[r] = fmaxf(vm[r], sv[r]);
        }
      }
      float mx = fmaxf(fmaxf(vm[0], vm[1]), fmaxf(vm[2], vm[3]));
      mx = fmaxf(mx, __shfl_xor(mx, 16));
      mx = fmaxf(mx, __shfl_xor(mx, 32));
      f32x4 vs = zero;
      #pragma unroll
      for (int jt = 0; jt < 4; ++jt) {
        #pragma unroll
        for (int r = 0; r < 4; ++r) {
          float p = __expf(pv4[jt][r] - mx);
          pv4[jt][r] = p;
          vs[r] += p;
        }
      }
      float sm = (vs[0] + vs[1]) + (vs[2] + vs[3]);
      sm += __shfl_xor(sm, 16);
      sm += __shfl_xor(sm, 32);
      float rv = 1.0f / sm;
      #pragma unroll
      for (int jt = 0; jt < 4; ++jt) {
        unsigned int lo = (unsigned int)f2bf(pv4[jt][0] * rv) | ((unsigned int)f2bf(pv4[jt][1] * rv) << 16);
        unsigned int hi = (unsigned int)f2bf(pv4[jt][2] * rv) | ((unsigned int)f2bf(pv4[jt][3] * rv) << 16);
        u32x2 w = {lo, hi};
        *(u32x2*)(pl + i * PLD + jt * 16 + 4 * g) = w;
      }
    }

    // O = P @ V, SWAPPED: oacc[it][dt] r -> d = dt*16+4g+r, i = it*16+q (lane-local)
    f32x4 oacc[4][2] = {};
    #pragma unroll
    for (int ktt = 0; ktt < 2; ++ktt) {
      bf16x8 pa[4];
      #pragma unroll
      for (int it = 0; it < 4; ++it)
        pa[it] = *(const bf16x8*)(pl + (it * 16 + q) * PLD + ktt * 32 + 8 * g);
      __builtin_amdgcn_s_setprio(1);
      #pragma unroll
      for (int it = 0; it < 4; ++it)
        #pragma unroll
        for (int dt = 0; dt < 2; ++dt)
          oacc[it][dt] = __builtin_amdgcn_mfma_f32_16x16x32_bf16(bv[ktt][dt], pa[it], oacc[it][dt], 0, 0, 0);
      __builtin_amdgcn_s_setprio(0);
    }

    // store: per lane float4 at [b*49+i][h*32 + dt*16 + 4g], i lane-local
    #pragma unroll
    for (int it = 0; it < 4; ++it) {
      int i = it * 16 + q;
      if (i < 49) {
        float* orow = out + (size_t)(b * 49 + i) * 512 + h * 32 + 4 * g;
        #pragma unroll
        for (int dt = 0; dt < 2; ++dt)
          *(f32x4*)(orow + dt * 16) = oacc[it][dt];
      }
    }

    if (hh < 3) {
      #pragma unroll
      for (int jt = 0; jt < 4; ++jt) ak[jt] = akn[jt];
      #pragma unroll
      for (int it = 0; it < 4; ++it) bq[it] = bqn[it];
    }
  }
}

// ---------------- launcher ----------------
extern "C" void kernel_launch(void* const* d_in, const int* in_sizes, int n_in,
                              void* d_out, int out_size, void* d_ws, size_t ws_size,
                              hipStream_t stream) {
  const float* x     = (const float*)d_in[0];
  const float* mask  = (const float*)d_in[1];
  const float* qkv_w = (const float*)d_in[2];
  const float* qkv_b = (const float*)d_in[3];
  const float* rpb   = (const float*)d_in[4];
  float* out = (float*)d_out;

  // workspace layout (bytes)
  const size_t QS_OFF   = 0;                         // 2048*16*49*32*2 = 102,760,448
  const size_t KK_OFF   = 102760448;
  const size_t VT_OFF   = 205520896;                 // 2048*16*32*56*2 = 117,440,512
  const size_t BIAS_OFF = 322961408;                 // 16*2548*2      = 81,536
  const size_t WB_OFF   = 323042944;                 // 1536*512*2     = 1,572,864
  const size_t NEED     = 324615808;
  if (ws_size < NEED) return;

  char* ws = (char*)d_ws;
  unsigned short* qsb   = (unsigned short*)(ws + QS_OFF);
  unsigned short* kkb   = (unsigned short*)(ws + KK_OFF);
  unsigned short* vtb   = (unsigned short*)(ws + VT_OFF);
  unsigned short* biasT = (unsigned short*)(ws + BIAS_OFF);
  unsigned short* wb    = (unsigned short*)(ws + WB_OFF);

  // xb (bf16 x, 103 MB) lives in d_out (205 MB fp32) — dead until win_attn
  // fully overwrites it.
  unsigned short* xb = (unsigned short*)d_out;

  conv_f2b_k<<<2048, 256, 0, stream>>>(x, xb, 6422528);        // 100352*512/8
  conv_f2b_k<<<512, 256, 0, stream>>>(qkv_w, wb, 98304);       // 1536*512/8
  build_bias_k<<<160, 256, 0, stream>>>(rpb, biasT);           // 16*2548
  qkv_gemm_k<<<9408, 256, 0, stream>>>(xb, qkv_b, wb, qsb, kkb, vtb);
  win_attn_k<<<2048, 256, 0, stream>>>(qsb, kkb, vtb, biasT, mask, out);
}

// Round 14
// 429.941 us; speedup vs baseline: 1.2587x; 1.0434x over previous
//
#include <hip/hip_runtime.h>
#include <cstdint>
#include <cstddef>

typedef __bf16 bf16x8 __attribute__((ext_vector_type(8)));
typedef float f32x4 __attribute__((ext_vector_type(4)));
typedef unsigned short u16x8 __attribute__((ext_vector_type(8)));
typedef unsigned short u16x4 __attribute__((ext_vector_type(4)));
typedef unsigned int u32x2 __attribute__((ext_vector_type(2)));

#define VT_LD 56   // padded j-stride of V^T rows
#define BSTRIDE 52 // bias/mask row stride (elements)
#define BSZ 2548   // 49*52 per head
#define PLD 80     // P LDS row stride (shorts)

__device__ __forceinline__ unsigned short f2bf(float f) {
  unsigned int u = __builtin_bit_cast(unsigned int, f);
  u += 0x7FFFu + ((u >> 16) & 1u);   // RNE
  return (unsigned short)(u >> 16);
}
__device__ __forceinline__ float bf2f(unsigned short h) {
  unsigned int u = (unsigned int)h << 16;
  return __builtin_bit_cast(float, u);
}

__device__ __forceinline__ void gload_lds16(const void* g, void* l) {
  __builtin_amdgcn_global_load_lds((const __attribute__((address_space(1))) void*)g,
                                   (__attribute__((address_space(3))) void*)l, 16, 0, 0);
}

// ---------------- kernel 0: generic fp32 -> bf16 (vec8, grid-stride) ----------------
__global__ void conv_f2b_k(const float* __restrict__ src, unsigned short* __restrict__ dst, long n8) {
  long i = (long)blockIdx.x * blockDim.x + threadIdx.x;
  long stride = (long)gridDim.x * blockDim.x;
  for (; i < n8; i += stride) {
    float4 a = *(const float4*)(src + i * 8);
    float4 b = *(const float4*)(src + i * 8 + 4);
    u16x8 p;
    p[0]=f2bf(a.x); p[1]=f2bf(a.y); p[2]=f2bf(a.z); p[3]=f2bf(a.w);
    p[4]=f2bf(b.x); p[5]=f2bf(b.y); p[6]=f2bf(b.z); p[7]=f2bf(b.w);
    *(u16x8*)(dst + i * 8) = p;
  }
}

// ---------------- kernel 0b: bias table bf16 [16][49][52] (pad cols 49..51 = 0) ----------------
__global__ void build_bias_k(const float* __restrict__ rpb, unsigned short* __restrict__ biasT) {
  int idx = blockIdx.x * 256 + threadIdx.x;
  if (idx >= 16 * BSZ) return;
  int h = idx / BSZ;
  int rem = idx - h * BSZ;
  int i = rem / BSTRIDE, j = rem - (rem / BSTRIDE) * BSTRIDE;
  unsigned short v = 0;
  if (j < 49) {
    int r1 = i / 7, c1 = i - r1 * 7;
    int r2 = j / 7, c2 = j - r2 * 7;
    int ri = (r1 - r2 + 6) * 13 + (c1 - c2 + 6);
    v = f2bf(rpb[ri * 16 + h]);
  }
  biasT[idx] = v;
}

// ================= 256x256 8-phase GEMM (T2+T3+T4+T5 template port) =================
// BM=BN=256, BK=64, 512 thr (8 waves 2x4), LDS 128 KB = 2 dbuf x (A 32K + B 32K).
// Per operand tile: 2 planes [256][32] shorts (64B rows), chunk-swizzle c^((row>>1)&3)
// -> identical zero-conflict ds_read_b128 geometry as the measured 128^2 kernel.
// K=512 -> 8 K-tiles; tile t in buf t&1. Stage stream for tile T:
//   (T-2).ph3: B half0 | (T-2).ph4: B half1 + A half0 | (T-1).ph1: A half1
// (each half = 128 rows x 64 k = 16 KB = 2 gload_lds/thread). Consumption of buf b
// finishes: B h0/h1 after ph2, A h0/h1 after ph3 -> every stage call is >=1 barrier
// after the last read of its region. vmcnt(6) once per tile at ph4 guarantees the
// next tile resident (6 = calls issued after its last stage call).

// stage one half-tile (2 planes) of A or B for K-tile KT into buf KT&1
#define STGA_H(KT, H) do {                                                                  \
    gload_lds16(ags + (size_t)(H)*65536 + (KT)*64,      Ab + ((KT)&1)*16384 + (H)*4096 + wid*512);        \
    gload_lds16(ags + (size_t)(H)*65536 + (KT)*64 + 32, Ab + ((KT)&1)*16384 + 8192 + (H)*4096 + wid*512); \
  } while (0)
#define STGB_H(KT, H) do {                                                                  \
    gload_lds16(bgs + (size_t)(H)*65536 + (KT)*64,      Bb + ((KT)&1)*16384 + (H)*4096 + wid*512);        \
    gload_lds16(bgs + (size_t)(H)*65536 + (KT)*64 + 32, Bb + ((KT)&1)*16384 + 8192 + (H)*4096 + wid*512); \
  } while (0)

// one MFMA quadrant: 4 row-tiles x 2 col-tiles x 2 k-subtiles = 16 MFMA
#define MPH(R2, C2, BF, SWAPPED) do {                                                       \
    __builtin_amdgcn_s_setprio(1);                                                          \
    _Pragma("unroll")                                                                       \
    for (int rtl = 0; rtl < 4; ++rtl)                                                       \
      _Pragma("unroll")                                                                     \
      for (int ctl = 0; ctl < 2; ++ctl)                                                     \
        _Pragma("unroll")                                                                   \
        for (int ks2 = 0; ks2 < 2; ++ks2)                                                   \
          acc[(R2)*4+rtl][(C2)*2+ctl] = (SWAPPED)                                           \
            ? __builtin_amdgcn_mfma_f32_16x16x32_bf16(BF[ctl][ks2], af[rtl][ks2], acc[(R2)*4+rtl][(C2)*2+ctl], 0, 0, 0) \
            : __builtin_amdgcn_mfma_f32_16x16x32_bf16(af[rtl][ks2], BF[ctl][ks2], acc[(R2)*4+rtl][(C2)*2+ctl], 0, 0, 0); \
    __builtin_amdgcn_s_setprio(0);                                                          \
  } while (0)

#define TILE256(KT, BUF, SWAPPED) do {                                                      \
    /* phase 1: read A(r2=0) + B(c2=0); stage A[KT+1] h1 */                                 \
    _Pragma("unroll")                                                                       \
    for (int rtl = 0; rtl < 4; ++rtl) {                                                     \
      af[rtl][0] = *(const bf16x8*)(arp + (BUF)*16384 + rtl*512);                           \
      af[rtl][1] = *(const bf16x8*)(arp + (BUF)*16384 + 8192 + rtl*512);                    \
    }                                                                                       \
    _Pragma("unroll")                                                                       \
    for (int ctl = 0; ctl < 2; ++ctl) {                                                     \
      bf0[ctl][0] = *(const bf16x8*)(brp + (BUF)*16384 + ctl*512);                          \
      bf0[ctl][1] = *(const bf16x8*)(brp + (BUF)*16384 + 8192 + ctl*512);                   \
    }                                                                                       \
    if ((KT) + 1 < 8) { STGA_H((KT)+1, 1); }                                                \
    __builtin_amdgcn_s_barrier();                                                           \
    MPH(0, 0, bf0, SWAPPED);                                                                \
    __builtin_amdgcn_s_barrier();                                                           \
    /* phase 2: read B(c2=1) */                                                             \
    _Pragma("unroll")                                                                       \
    for (int ctl = 0; ctl < 2; ++ctl) {                                                     \
      bf1[ctl][0] = *(const bf16x8*)(brp + (BUF)*16384 + 1024 + ctl*512);                   \
      bf1[ctl][1] = *(const bf16x8*)(brp + (BUF)*16384 + 8192 + 1024 + ctl*512);            \
    }                                                                                       \
    __builtin_amdgcn_s_barrier();                                                           \
    MPH(0, 1, bf1, SWAPPED);                                                                \
    __builtin_amdgcn_s_barrier();                                                           \
    /* phase 3: read A(r2=1); stage B[KT+2] h0 */                                           \
    _Pragma("unroll")                                                                       \
    for (int rtl = 0; rtl < 4; ++rtl) {                                                     \
      af[rtl][0] = *(const bf16x8*)(arp + (BUF)*16384 + 2048 + rtl*512);                    \
      af[rtl][1] = *(const bf16x8*)(arp + (BUF)*16384 + 8192 + 2048 + rtl*512);             \
    }                                                                                       \
    if ((KT) + 2 < 8) { STGB_H((KT)+2, 0); }                                                \
    __builtin_amdgcn_s_barrier();                                                           \
    MPH(1, 1, bf1, SWAPPED);                                                                \
    __builtin_amdgcn_s_barrier();                                                           \
    /* phase 4: stage B[KT+2] h1 + A[KT+2] h0; counted vmcnt */                             \
    if ((KT) + 2 < 8) {                                                                     \
      STGB_H((KT)+2, 1); STGA_H((KT)+2, 0);                                                 \
      asm volatile("s_waitcnt vmcnt(6)" ::: "memory");                                      \
    } else if ((KT) + 1 < 8) {                                                              \
      asm volatile("s_waitcnt vmcnt(0)" ::: "memory");                                      \
    }                                                                                       \
    __builtin_amdgcn_s_barrier();                                                           \
    MPH(1, 0, bf0, SWAPPED);                                                                \
    __builtin_amdgcn_s_barrier();                                                           \
  } while (0)

__global__ __launch_bounds__(512, 2) void qkv_gemm256_k(
    const unsigned short* __restrict__ xb, const float* __restrict__ qkv_b,
    const unsigned short* __restrict__ wb,
    unsigned short* __restrict__ qs, unsigned short* __restrict__ kk,
    unsigned short* __restrict__ vt)
{
  __shared__ __align__(16) unsigned short smem[65536];   // 128 KB
  unsigned short* Ab = smem;            // [2 buf][2 planes][256][32]
  unsigned short* Bb = smem + 32768;

  int bid = blockIdx.x;
  int sw = (bid & 7) * 294 + (bid >> 3);   // 2352 % 8 == 0 -> bijective XCD swizzle
  int mt = sw / 6, nt = sw - mt * 6;       // 6 nt share one A panel
  long m0 = (long)mt * 256;
  int  n0 = nt * 256;
  int  s  = n0 >> 9;                       // nt 0,1->Q  2,3->K  4,5->V

  int t = threadIdx.x;
  int lane = t & 63, wid = t >> 6;
  int g = lane >> 4, q = lane & 15;
  int wm = wid >> 2, wn = wid & 3;         // 2 x 4 wave grid

  f32x4 acc[8][4] = {};
  bf16x8 af[4][2], bf0[2][2], bf1[2][2];

  // staging: thread covers row (t>>2) of a 128-row half, inverse-swizzled chunk
  int schunk = (t & 3) ^ ((t >> 3) & 3);
  const unsigned short* ags = xb + (m0 + (t >> 2)) * 512 + schunk * 8;
  const unsigned short* bgs = wb + (size_t)(n0 + (t >> 2)) * 512 + schunk * 8;

  // frag-read bases (swizzled slot; (row>>1)&3 == (q>>1)&3 for all our rows)
  int slot = (g ^ ((q >> 1) & 3)) * 8;
  const unsigned short* arp = Ab + (wm * 128 + q) * 32 + slot;
  const unsigned short* brp = Bb + (wn * 64 + q) * 32 + slot;

  // prologue: tile0 full (8 calls) + tile1 Bh0,Bh1,Ah0 (6 calls); tile1 Ah1 at t0.ph1
  STGB_H(0, 0); STGB_H(0, 1); STGA_H(0, 0); STGA_H(0, 1);
  STGB_H(1, 0); STGB_H(1, 1); STGA_H(1, 0);
  asm volatile("s_waitcnt vmcnt(6)" ::: "memory");
  __builtin_amdgcn_s_barrier();

  if (s < 2) {
    for (int kp = 0; kp < 4; ++kp) {
      TILE256(2 * kp, 0, 1);
      TILE256(2 * kp + 1, 1, 1);
    }
    // Q/K epilogue (swapped): m = m0+wm*128+rt*16+q lane-local; n = n0+wn*64+ct*16+4g+r
    unsigned short* dst = (s == 0) ? qs : kk;
    float sc2 = (s == 0) ? 0.17677669529663687f : 1.0f;
    float4 bi[4]; int hj[4], dj[4];
    #pragma unroll
    for (int ct = 0; ct < 4; ++ct) {
      int n4 = n0 + wn * 64 + ct * 16 + 4 * g;
      bi[ct] = *(const float4*)(qkv_b + n4);
      hj[ct] = (n4 >> 5) & 15;
      dj[ct] = n4 & 31;
    }
    #pragma unroll
    for (int rt = 0; rt < 8; ++rt) {
      unsigned int m = (unsigned int)m0 + wm * 128 + rt * 16 + q;
      unsigned int b = m / 49;
      unsigned int i = m - b * 49;
      size_t base = ((size_t)(b * 16) * 49 + i) * 32;
      #pragma unroll
      for (int ct = 0; ct < 4; ++ct) {
        f32x4 a = acc[rt][ct];
        unsigned int lo = (unsigned int)f2bf((a[0] + bi[ct].x) * sc2) | ((unsigned int)f2bf((a[1] + bi[ct].y) * sc2) << 16);
        unsigned int hi = (unsigned int)f2bf((a[2] + bi[ct].z) * sc2) | ((unsigned int)f2bf((a[3] + bi[ct].w) * sc2) << 16);
        u32x2 wv2 = {lo, hi};
        *(u32x2*)(dst + base + (size_t)hj[ct] * 1568 + dj[ct]) = wv2;
      }
    }
  } else {
    for (int kp = 0; kp < 4; ++kp) {
      TILE256(2 * kp, 0, 0);
      TILE256(2 * kp + 1, 1, 0);
    }
    // V epilogue (normal): 4 consecutive i in VT -> packed dword stores
    #pragma unroll
    for (int ct = 0; ct < 4; ++ct) {
      int n = n0 + wn * 64 + ct * 16 + q;
      float bias = qkv_b[n];
      int d = n & 31;
      int h = (n >> 5) & 15;
      #pragma unroll
      for (int rt = 0; rt < 8; ++rt) {
        unsigned int gm0 = (unsigned int)m0 + wm * 128 + rt * 16 + 4 * g;
        unsigned int b0 = gm0 / 49;
        unsigned int i0 = gm0 - b0 * 49;
        unsigned short hv[4];
        #pragma unroll
        for (int r = 0; r < 4; ++r) hv[r] = f2bf(acc[rt][ct][r] + bias);
        if (i0 <= 45) {
          unsigned short* base = vt + ((size_t)(b0 * 16 + h) * 32 + d) * VT_LD;
          if ((i0 & 1) == 0) {
            *(unsigned int*)(base + i0)     = (unsigned int)hv[0] | ((unsigned int)hv[1] << 16);
            *(unsigned int*)(base + i0 + 2) = (unsigned int)hv[2] | ((unsigned int)hv[3] << 16);
          } else {
            base[i0] = hv[0];
            *(unsigned int*)(base + i0 + 1) = (unsigned int)hv[1] | ((unsigned int)hv[2] << 16);
            base[i0 + 3] = hv[3];
          }
        } else {
          #pragma unroll
          for (int r = 0; r < 4; ++r) {
            unsigned int gm = gm0 + r;
            unsigned int b = gm / 49;
            unsigned int i = gm - b * 49;
            vt[((size_t)(b * 16 + h) * 32 + d) * VT_LD + i] = hv[r];
          }
        }
      }
    }
  }
}

// ---------------- kernel 2: fused window attention (R13-verbatim) ----------------
__global__ __launch_bounds__(256, 2) void win_attn_k(
    const unsigned short* __restrict__ qs, const unsigned short* __restrict__ kk,
    const unsigned short* __restrict__ vt, const unsigned short* __restrict__ biasT,
    const float* __restrict__ mask, float* __restrict__ out)
{
  __shared__ float mlds[BSZ];
  __shared__ unsigned short plds[4][64 * PLD];

  int b = blockIdx.x;
  int t = threadIdx.x;
  int lane = t & 63, wv = t >> 6;
  int g = lane >> 4, q = lane & 15;

  const float* msrc = mask + (size_t)(b & 63) * 2401;
  for (int idx = t; idx < BSZ; idx += 256) {
    int i = idx / BSTRIDE, j = idx - (idx / BSTRIDE) * BSTRIDE;
    mlds[idx] = (j < 49) ? msrc[i * 49 + j] : 0.0f;
  }
  __syncthreads();

  unsigned short* pl = plds[wv];
  const float NINF = -__builtin_inff();

  int rc[4];
  rc[0] = q; rc[1] = 16 + q; rc[2] = 32 + q; rc[3] = 48;

  int h0 = wv * 4;
  const unsigned short* qh = qs + (size_t)(b * 16 + h0) * (49 * 32);
  const unsigned short* kh = kk + (size_t)(b * 16 + h0) * (49 * 32);
  bf16x8 ak[4], bq[4];
  #pragma unroll
  for (int jt = 0; jt < 4; ++jt) ak[jt] = *(const bf16x8*)(kh + rc[jt] * 32 + 8 * g);
  #pragma unroll
  for (int it = 0; it < 4; ++it) bq[it] = *(const bf16x8*)(qh + rc[it] * 32 + 8 * g);

  #pragma unroll
  for (int hh = 0; hh < 4; ++hh) {
    int h = wv * 4 + hh;
    const unsigned short* vh  = vt + (size_t)(b * 16 + h) * (32 * VT_LD);
    const unsigned short* bh2 = biasT + h * BSZ;

    f32x4 zero = {0.f, 0.f, 0.f, 0.f};
    f32x4 st[4][4];
    __builtin_amdgcn_s_setprio(1);
    #pragma unroll
    for (int it = 0; it < 4; ++it)
      #pragma unroll
      for (int jt = 0; jt < 4; ++jt)
        st[it][jt] = __builtin_amdgcn_mfma_f32_16x16x32_bf16(ak[jt], bq[it], zero, 0, 0, 0);
    __builtin_amdgcn_s_setprio(0);

    bf16x8 akn[4], bqn[4];
    if (hh < 3) {
      const unsigned short* qh2 = qh + 49 * 32;
      const unsigned short* kh2 = kh + 49 * 32;
      #pragma unroll
      for (int jt = 0; jt < 4; ++jt) akn[jt] = *(const bf16x8*)(kh2 + rc[jt] * 32 + 8 * g);
      #pragma unroll
      for (int it = 0; it < 4; ++it) bqn[it] = *(const bf16x8*)(qh2 + rc[it] * 32 + 8 * g);
      qh = qh2; kh = kh2;
    }
    bf16x8 bv[2][2];
    #pragma unroll
    for (int ktt = 0; ktt < 2; ++ktt)
      #pragma unroll
      for (int dt = 0; dt < 2; ++dt)
        bv[ktt][dt] = *(const bf16x8*)(vh + (dt * 16 + q) * VT_LD + ktt * 32 + 8 * g);

    #pragma unroll
    for (int it = 0; it < 4; ++it) {
      int i = it * 16 + q;
      int ic = i > 48 ? 48 : i;
      f32x4 pv4[4];
      f32x4 vm = {NINF, NINF, NINF, NINF};
      #pragma unroll
      for (int jt = 0; jt < 4; ++jt) {
        if (jt == 3 && g > 0) {
          pv4[3] = (f32x4){NINF, NINF, NINF, NINF};
        } else {
          u16x4 bu = *(const u16x4*)(bh2 + ic * BSTRIDE + jt * 16 + 4 * g);
          f32x4 m4 = *(const f32x4*)(mlds + ic * BSTRIDE + jt * 16 + 4 * g);
          f32x4 sv = st[it][jt];
          #pragma unroll
          for (int r = 0; r < 4; ++r) sv[r] += bf2f(bu[r]) + m4[r];
          if (jt == 3) {
            sv[1] = NINF; sv[2] = NINF; sv[3] = NINF;
          }
          pv4[jt] = sv;
          #pragma unroll
          for (int r = 0; r < 4; ++r) vm[r] = fmaxf(vm[r], sv[r]);
        }
      }
      float mx = fmaxf(fmaxf(vm[0], vm[1]), fmaxf(vm[2], vm[3]));
      mx = fmaxf(mx, __shfl_xor(mx, 16));
      mx = fmaxf(mx, __shfl_xor(mx, 32));
      f32x4 vs = zero;
      #pragma unroll
      for (int jt = 0; jt < 4; ++jt) {
        #pragma unroll
        for (int r = 0; r < 4; ++r) {
          float p = __expf(pv4[jt][r] - mx);
          pv4[jt][r] = p;
          vs[r] += p;
        }
      }
      float sm = (vs[0] + vs[1]) + (vs[2] + vs[3]);
      sm += __shfl_xor(sm, 16);
      sm += __shfl_xor(sm, 32);
      float rv = 1.0f / sm;
      #pragma unroll
      for (int jt = 0; jt < 4; ++jt) {
        unsigned int lo = (unsigned int)f2bf(pv4[jt][0] * rv) | ((unsigned int)f2bf(pv4[jt][1] * rv) << 16);
        unsigned int hi = (unsigned int)f2bf(pv4[jt][2] * rv) | ((unsigned int)f2bf(pv4[jt][3] * rv) << 16);
        u32x2 w = {lo, hi};
        *(u32x2*)(pl + i * PLD + jt * 16 + 4 * g) = w;
      }
    }

    f32x4 oacc[4][2] = {};
    #pragma unroll
    for (int ktt = 0; ktt < 2; ++ktt) {
      bf16x8 pa[4];
      #pragma unroll
      for (int it = 0; it < 4; ++it)
        pa[it] = *(const bf16x8*)(pl + (it * 16 + q) * PLD + ktt * 32 + 8 * g);
      __builtin_amdgcn_s_setprio(1);
      #pragma unroll
      for (int it = 0; it < 4; ++it)
        #pragma unroll
        for (int dt = 0; dt < 2; ++dt)
          oacc[it][dt] = __builtin_amdgcn_mfma_f32_16x16x32_bf16(bv[ktt][dt], pa[it], oacc[it][dt], 0, 0, 0);
      __builtin_amdgcn_s_setprio(0);
    }

    #pragma unroll
    for (int it = 0; it < 4; ++it) {
      int i = it * 16 + q;
      if (i < 49) {
        float* orow = out + (size_t)(b * 49 + i) * 512 + h * 32 + 4 * g;
        #pragma unroll
        for (int dt = 0; dt < 2; ++dt)
          *(f32x4*)(orow + dt * 16) = oacc[it][dt];
      }
    }

    if (hh < 3) {
      #pragma unroll
      for (int jt = 0; jt < 4; ++jt) ak[jt] = akn[jt];
      #pragma unroll
      for (int it = 0; it < 4; ++it) bq[it] = bqn[it];
    }
  }
}

// ---------------- launcher ----------------
extern "C" void kernel_launch(void* const* d_in, const int* in_sizes, int n_in,
                              void* d_out, int out_size, void* d_ws, size_t ws_size,
                              hipStream_t stream) {
  const float* x     = (const float*)d_in[0];
  const float* mask  = (const float*)d_in[1];
  const float* qkv_w = (const float*)d_in[2];
  const float* qkv_b = (const float*)d_in[3];
  const float* rpb   = (const float*)d_in[4];
  float* out = (float*)d_out;

  // workspace layout (bytes)
  const size_t QS_OFF   = 0;                         // 2048*16*49*32*2 = 102,760,448
  const size_t KK_OFF   = 102760448;
  const size_t VT_OFF   = 205520896;                 // 2048*16*32*56*2 = 117,440,512
  const size_t BIAS_OFF = 322961408;                 // 16*2548*2      = 81,536
  const size_t WB_OFF   = 323042944;                 // 1536*512*2     = 1,572,864
  const size_t NEED     = 324615808;
  if (ws_size < NEED) return;

  char* ws = (char*)d_ws;
  unsigned short* qsb   = (unsigned short*)(ws + QS_OFF);
  unsigned short* kkb   = (unsigned short*)(ws + KK_OFF);
  unsigned short* vtb   = (unsigned short*)(ws + VT_OFF);
  unsigned short* biasT = (unsigned short*)(ws + BIAS_OFF);
  unsigned short* wb    = (unsigned short*)(ws + WB_OFF);

  // xb (bf16 x, 103 MB) lives in d_out (205 MB fp32) — dead until win_attn
  // fully overwrites it.
  unsigned short* xb = (unsigned short*)d_out;

  conv_f2b_k<<<2048, 256, 0, stream>>>(x, xb, 6422528);        // 100352*512/8
  conv_f2b_k<<<512, 256, 0, stream>>>(qkv_w, wb, 98304);       // 1536*512/8
  build_bias_k<<<160, 256, 0, stream>>>(rpb, biasT);           // 16*2548
  qkv_gemm256_k<<<2352, 512, 0, stream>>>(xb, qkv_b, wb, qsb, kkb, vtb);
  win_attn_k<<<2048, 256, 0, stream>>>(qsb, kkb, vtb, biasT, mask, out);
}